// Round 11
// baseline (528.036 us; speedup 1.0000x reference)
//
#include <hip/hip_runtime.h>
#include <stddef.h>

#define TBN_EPS 1e-5f
#define ELLK 32          // Poisson(16): P(deg>32)~1.4e-4 -> ~7 nodes overflow
#define MAXOVF 4096
#define PSH 9            // 512-node partitions; class = (part & 7)
#define P2N 512          // nodes per phase-2 partition
#define REP 16           // stat replica slots

typedef short sv8 __attribute__((ext_vector_type(8)));     // 8 bf16 (4 VGPRs)
typedef float fv4 __attribute__((ext_vector_type(4)));     // MFMA C/D

__device__ inline unsigned short f2bf(float f) {  // RNE float -> bf16 bits
  unsigned u = __float_as_uint(f);
  u += 0x7FFF + ((u >> 16) & 1);
  return (unsigned short)(u >> 16);
}
__device__ inline float bf2f(unsigned short h) {
  return __uint_as_float(((unsigned)h) << 16);
}

// ---------------- phase 1: class-sort private edge chunks ----------------
// Each block owns a contiguous chunk of <=1024 edges, sorts them by class
// ((dst>>PSH)&7) in LDS, and writes one packed (src|dst<<16) segment to a
// PRIVATE region (fully coalesced) + an 8-entry length row. Zero scattered
// global writes; edge list read exactly once.
__global__ __launch_bounds__(256) void k_bucket(
    const int* __restrict__ ei, unsigned* __restrict__ seg,
    int* __restrict__ lens, int E, int chunk) {
  __shared__ int s_nz;
  __shared__ int s_cnt[8], s_pos[8];
  __shared__ unsigned s_buf[1024];
  int b = blockIdx.x, tid = threadIdx.x;
  if (tid == 0) s_nz = 0;
  if (tid < 8) s_cnt[tid] = 0;
  __syncthreads();
  {
    int idx = 2 * tid + 1;
    int v = (idx < E) ? ei[idx] : 0;   // odd dwords: i64 high-halves (all 0) vs i32 payload
    if (v != 0) atomicOr(&s_nz, 1);
  }
  __syncthreads();
  bool i64 = (s_nz == 0);
  const int2* ei64s = (const int2*)ei;
  const int2* ei64d = (const int2*)(ei + 2 * (size_t)E);
  int e0 = b * chunk;
  int ecnt = E - e0;
  ecnt = (ecnt < chunk) ? ecnt : chunk;
  if (ecnt < 0) ecnt = 0;
  unsigned pk[4];
  int cls[4];
  int nk = 0;
  for (int i = tid; i < ecnt; i += 256, ++nk) {
    int e = e0 + i;
    int d = i64 ? ei64d[e].x : ei[(size_t)E + e];
    int s = i64 ? ei64s[e].x : ei[e];
    pk[nk] = (unsigned)(s & 0xFFFF) | ((unsigned)d << 16);
    cls[nk] = (d >> PSH) & 7;
    atomicAdd(&s_cnt[cls[nk]], 1);
  }
  __syncthreads();
  if (tid == 0) {
    int acc = 0;
#pragma unroll
    for (int c = 0; c < 8; ++c) { s_pos[c] = acc; acc += s_cnt[c]; }
  }
  __syncthreads();
  for (int k = 0; k < nk; ++k) {
    int p = atomicAdd(&s_pos[cls[k]], 1);
    s_buf[p] = pk[k];
  }
  __syncthreads();
  unsigned* out = seg + (size_t)b * chunk;
  for (int i = tid; i < ecnt; i += 256) out[i] = s_buf[i];
  if (tid < 8) lens[b * 8 + tid] = s_cnt[tid];
}

// ---------------- phase 2: per-partition LDS ELL assembly ----------------
// One block per 512-node partition. Threads stripe over block-segments of
// their class, filter to this partition, assemble ELL+cnt in LDS, then one
// coalesced 32KB writeout. Same-row stores are LDS -> write amplification = 1.
__global__ __launch_bounds__(256) void k_build(
    const unsigned* __restrict__ seg, const int* __restrict__ lens,
    int* __restrict__ cnt, unsigned short* __restrict__ ell,
    int* __restrict__ ovf, int* __restrict__ ocnt,
    int nb, int chunk, int n) {
  __shared__ unsigned short s_ell[P2N * ELLK];   // 32 KB
  __shared__ int s_cnt[P2N];                     // 2 KB
  int p = blockIdx.x, tid = threadIdx.x;
  int c = p & 7;
  int node0 = p << PSH;
  for (int i = tid; i < P2N; i += 256) s_cnt[i] = 0;
  __syncthreads();
  for (int b = tid; b < nb; b += 256) {
    const int* lr = &lens[b * 8];
    int beg = 0;
    for (int u = 0; u < 8; ++u) {
      int lv = lr[u];
      if (u == c) {
        const unsigned* sp = seg + (size_t)b * chunk + beg;
        for (int i = 0; i < lv; ++i) {
          unsigned pkv = sp[i];
          int d = (int)(pkv >> 16);
          if ((d >> PSH) == p) {
            int pos = atomicAdd(&s_cnt[d & (P2N - 1)], 1);
            if (pos < ELLK) {
              s_ell[(d & (P2N - 1)) * ELLK + pos] = (unsigned short)(pkv & 0xFFFF);
            } else {
              int o = atomicAdd(ocnt, 1);
              if (o < MAXOVF) { ovf[2 * o] = (int)(pkv & 0xFFFF); ovf[2 * o + 1] = d; }
            }
          }
        }
        break;
      }
      beg += lv;
    }
  }
  __syncthreads();
  int rows = n - node0;
  rows = (rows < P2N) ? rows : P2N;
  if (rows <= 0) return;
  for (int i = tid; i < rows; i += 256) cnt[node0 + i] = s_cnt[i];
  // ELL slice: rows * 64B, coalesced uint4 writes
  int tot16 = rows * 4;
  const uint4* src4 = (const uint4*)s_ell;
  uint4* dst4 = (uint4*)(ell + (size_t)node0 * ELLK);
  for (int i = tid; i < tot16; i += 256) dst4[i] = src4[i];
}

// ------- merged: workspace zeroing + W -> MFMA fragments + x fp32->bf16 cast -------
#define ZBLK 64
__global__ __launch_bounds__(256) void k_prep(
    const float* __restrict__ x, unsigned short* __restrict__ xb, int total4,
    const float* __restrict__ W1, const float* __restrict__ W2,
    unsigned short* __restrict__ wbh, unsigned short* __restrict__ wbl,
    int* __restrict__ zbase, int zwords) {
  int b = blockIdx.x;
  if (b < 48) {  // W prep: 48 blocks = 8 x 3 layers x 2 matrices
    int bz = b / 24, by = (b % 24) / 8, bx = b % 8;
    int ent = bx * 256 + threadIdx.x;   // (kc*8+nt)*64+lane
    int lane = ent & 63;
    int t = ent >> 6;
    int nt = t & 7;
    int kc = t >> 3;
    const float* W = (bz ? W2 : W1) + (size_t)by * 16384;
    size_t mbase = (size_t)(bz * 3 + by) * 16384;
    int q = lane >> 4, cc = lane & 15;
    int col = nt * 16 + cc;
    size_t obase = mbase + (size_t)ent * 8;
#pragma unroll
    for (int j = 0; j < 8; ++j) {
      float w = W[(size_t)(kc * 32 + q * 8 + j) * 128 + col];
      unsigned short h = f2bf(w);
      unsigned short l = f2bf(w - bf2f(h));
      wbh[obase + j] = h;
      wbl[obase + j] = l;
    }
  } else if (b < 48 + ZBLK) {  // zero ocnt + ST (+cnt region, harmless)
    int i = (b - 48) * 256 + threadIdx.x;
    int stride = ZBLK * 256;
    for (; i < zwords; i += stride) zbase[i] = 0;
  } else {
    int i = (b - 48 - ZBLK) * 256 + threadIdx.x;
    if (i < total4) {
      float4 v = ((const float4*)x)[i];
      ushort4 o;
      o.x = f2bf(v.x); o.y = f2bf(v.y); o.z = f2bf(v.z); o.w = f2bf(v.w);
      ((ushort4*)xb)[i] = o;
    }
  }
}

// ---------------- gather: agg = (1+eps)*f(x[g]) + sum f(x[src]), bf16 + ELL -------
// Wave-uniform scalar index loads; overflow rows scan the tiny ovf list inline.
template <bool BN>
__global__ __launch_bounds__(256, 8) void k_gather(
    const unsigned short* __restrict__ xin, const float* __restrict__ stats,
    const float* __restrict__ gamma, const float* __restrict__ beta, float inv_n,
    const int* __restrict__ cnt, const unsigned short* __restrict__ ell,
    const int* __restrict__ ovf, const int* __restrict__ ocnt,
    const float* __restrict__ eps_arr, int layer, float* __restrict__ agg, int n) {
  __shared__ float s_sc[128], s_sh[128];
  if (BN) {
    int i = threadIdx.x;
    if (i < 128) {
      float s = 0.f, q = 0.f;
#pragma unroll
      for (int r = 0; r < REP; ++r) { s += stats[r * 256 + i]; q += stats[r * 256 + 128 + i]; }
      float m = s * inv_n;
      float var = q * inv_n - m * m;
      float scale = rsqrtf(var + TBN_EPS) * gamma[i];
      s_sc[i] = scale;
      s_sh[i] = beta[i] - m * scale;
    }
    __syncthreads();
  }
  int lane = threadIdx.x & 63;
  int wid = blockIdx.x * (blockDim.x >> 6) + (threadIdx.x >> 6);
  int nw = gridDim.x * (blockDim.x >> 6);
  float ep = 1.0f + eps_arr[layer];
  float sc0 = 1.f, sh0 = 0.f, sc1 = 1.f, sh1 = 0.f;
  if (BN) {
    float2 s2 = ((const float2*)s_sc)[lane];
    float2 h2 = ((const float2*)s_sh)[lane];
    sc0 = s2.x; sc1 = s2.y; sh0 = h2.x; sh1 = h2.y;
  }
  const unsigned* xb = (const unsigned*)xin;  // one dword = 2 bf16 cols
  for (int g = wid; g < n; g += nw) {
    int deg0 = cnt[g];
    int deg = (deg0 < ELLK) ? deg0 : ELLK;
    const unsigned short* row = ell + (size_t)g * ELLK;
    unsigned r = xb[(size_t)g * 64 + lane];
    float vx = __uint_as_float(r << 16);
    float vy = __uint_as_float(r & 0xFFFF0000u);
    if (BN) {
      vx = fmaxf(fmaf(vx, sc0, sh0), 0.f);
      vy = fmaxf(fmaf(vy, sc1, sh1), 0.f);
    }
    float ax = ep * vx, ay = ep * vy;
    int j = 0;
    for (; j + 7 < deg; j += 8) {
      unsigned rr[8];
#pragma unroll
      for (int jj = 0; jj < 8; ++jj) rr[jj] = xb[(size_t)row[j + jj] * 64 + lane];
#pragma unroll
      for (int jj = 0; jj < 8; ++jj) {
        float xv = __uint_as_float(rr[jj] << 16);
        float yv = __uint_as_float(rr[jj] & 0xFFFF0000u);
        if (BN) {
          xv = fmaxf(fmaf(xv, sc0, sh0), 0.f);
          yv = fmaxf(fmaf(yv, sc1, sh1), 0.f);
        }
        ax += xv; ay += yv;
      }
    }
    for (; j + 3 < deg; j += 4) {
      unsigned rr[4];
#pragma unroll
      for (int jj = 0; jj < 4; ++jj) rr[jj] = xb[(size_t)row[j + jj] * 64 + lane];
#pragma unroll
      for (int jj = 0; jj < 4; ++jj) {
        float xv = __uint_as_float(rr[jj] << 16);
        float yv = __uint_as_float(rr[jj] & 0xFFFF0000u);
        if (BN) {
          xv = fmaxf(fmaf(xv, sc0, sh0), 0.f);
          yv = fmaxf(fmaf(yv, sc1, sh1), 0.f);
        }
        ax += xv; ay += yv;
      }
    }
    for (; j < deg; ++j) {
      unsigned r0 = xb[(size_t)row[j] * 64 + lane];
      float x0 = __uint_as_float(r0 << 16), y0 = __uint_as_float(r0 & 0xFFFF0000u);
      if (BN) {
        x0 = fmaxf(fmaf(x0, sc0, sh0), 0.f);
        y0 = fmaxf(fmaf(y0, sc1, sh1), 0.f);
      }
      ax += x0; ay += y0;
    }
    if (deg0 > ELLK) {  // rare: scan tiny overflow list for this dst
      int oc = *ocnt;
      oc = (oc < MAXOVF) ? oc : MAXOVF;
      for (int i = 0; i < oc; ++i) {
        if (ovf[2 * i + 1] == g) {
          unsigned r0 = xb[(size_t)ovf[2 * i] * 64 + lane];
          float x0 = __uint_as_float(r0 << 16), y0 = __uint_as_float(r0 & 0xFFFF0000u);
          if (BN) {
            x0 = fmaxf(fmaf(x0, sc0, sh0), 0.f);
            y0 = fmaxf(fmaf(y0, sc1, sh1), 0.f);
          }
          ax += x0; ay += y0;
        }
      }
    }
    ((float2*)agg)[(size_t)g * 64 + lane] = make_float2(ax, ay);
  }
}

// ---------------- column stats: sum / sumsq per column -> REP-replicated table ----
template <bool BF16IN>
__global__ __launch_bounds__(256) void k_stats(
    const void* __restrict__ in, float* __restrict__ st, int n) {
  __shared__ float sm_sum[4][128], sm_sq[4][128];
  int tid = threadIdx.x;
  int c = tid & 63;       // handles cols 2c, 2c+1
  int rg = tid >> 6;      // 4 row-groups
  float s0 = 0.f, s1 = 0.f, q0 = 0.f, q1 = 0.f;
  for (int r = blockIdx.x * 4 + rg; r < n; r += gridDim.x * 4) {
    float a, b;
    if (BF16IN) {
      unsigned v = ((const unsigned*)in)[(size_t)r * 64 + c];
      a = __uint_as_float(v << 16);
      b = __uint_as_float(v & 0xFFFF0000u);
    } else {
      float2 v = ((const float2*)in)[(size_t)r * 64 + c];
      a = v.x; b = v.y;
    }
    s0 += a; s1 += b; q0 += a * a; q1 += b * b;
  }
  sm_sum[rg][2 * c] = s0; sm_sum[rg][2 * c + 1] = s1;
  sm_sq[rg][2 * c] = q0;  sm_sq[rg][2 * c + 1] = q1;
  __syncthreads();
  if (tid < 128) {
    float s = 0.f, q = 0.f;
#pragma unroll
    for (int g = 0; g < 4; ++g) { s += sm_sum[g][tid]; q += sm_sq[g][tid]; }
    float* base = st + (size_t)(blockIdx.x & (REP - 1)) * 256;
    atomicAdd(&base[tid], s);
    atomicAdd(&base[128 + tid], q);
  }
}

// ---------------- pure MFMA GEMM: one 64-row tile per block, B in LDS ----------------
// out = f(in) @ W + bias. bf16x3 split product. No stats, no atomics.
template <bool BN_IN, bool OUT_BF16>
__global__ __launch_bounds__(256) void k_gemm_mfma(
    const float* __restrict__ in, const float* __restrict__ bn_stats,
    const float* __restrict__ bn_gamma, const float* __restrict__ bn_beta, float inv_n,
    const unsigned short* __restrict__ wh, const unsigned short* __restrict__ wl,
    const float* __restrict__ bias, float* __restrict__ outf,
    unsigned short* __restrict__ outb, int n) {
  __shared__ unsigned short Bs[32768];   // 64 KB: [0..2047]=hi sv8, [2048..4095]=lo
  __shared__ float s_sc[128], s_sh[128];
  int tid = threadIdx.x;
  int wave = tid >> 6, lane = tid & 63;
  int q = lane >> 4, c = lane & 15;
  int t = blockIdx.x;
  int row = t * 64 + wave * 16 + c;
  bool valid = row < n;
  // A loads issued first — latency hides under B staging
  float4 va[8];
#pragma unroll
  for (int kc = 0; kc < 4; ++kc) {
    va[kc * 2] = make_float4(0.f, 0.f, 0.f, 0.f);
    va[kc * 2 + 1] = make_float4(0.f, 0.f, 0.f, 0.f);
    if (valid) {
      const float* p = &in[(size_t)row * 128 + kc * 32 + q * 8];
      va[kc * 2] = *(const float4*)p;
      va[kc * 2 + 1] = *(const float4*)(p + 4);
    }
  }
  // bulk cooperative B stage (pipelined 16B loads)
  {
    const sv8* whv = (const sv8*)wh;
    const sv8* wlv = (const sv8*)wl;
    sv8* bs = (sv8*)Bs;
#pragma unroll
    for (int r = 0; r < 8; ++r) {
      bs[tid + 256 * r] = whv[tid + 256 * r];
      bs[2048 + tid + 256 * r] = wlv[tid + 256 * r];
    }
  }
  if (BN_IN && tid < 128) {
    float s = 0.f, qq = 0.f;
#pragma unroll
    for (int r = 0; r < REP; ++r) { s += bn_stats[r * 256 + tid]; qq += bn_stats[r * 256 + 128 + tid]; }
    float m = s * inv_n;
    float var = qq * inv_n - m * m;
    float scale = rsqrtf(var + TBN_EPS) * bn_gamma[tid];
    s_sc[tid] = scale;
    s_sh[tid] = bn_beta[tid] - m * scale;
  }
  float bv[8];
#pragma unroll
  for (int nt = 0; nt < 8; ++nt) bv[nt] = bias[nt * 16 + c];
  const sv8* bsh = (const sv8*)Bs;
  const sv8* bsl = ((const sv8*)Bs) + 2048;
  __syncthreads();
  fv4 acc[8];
#pragma unroll
  for (int nt = 0; nt < 8; ++nt) acc[nt] = (fv4){0.f, 0.f, 0.f, 0.f};
#pragma unroll
  for (int kc = 0; kc < 4; ++kc) {
    float a[8];
    a[0] = va[kc * 2].x; a[1] = va[kc * 2].y; a[2] = va[kc * 2].z; a[3] = va[kc * 2].w;
    a[4] = va[kc * 2 + 1].x; a[5] = va[kc * 2 + 1].y;
    a[6] = va[kc * 2 + 1].z; a[7] = va[kc * 2 + 1].w;
    if (BN_IN) {
      const float4 s0 = *(const float4*)&s_sc[kc * 32 + q * 8];
      const float4 s1 = *(const float4*)&s_sc[kc * 32 + q * 8 + 4];
      const float4 h0 = *(const float4*)&s_sh[kc * 32 + q * 8];
      const float4 h1 = *(const float4*)&s_sh[kc * 32 + q * 8 + 4];
      a[0] = fmaxf(fmaf(a[0], s0.x, h0.x), 0.f);
      a[1] = fmaxf(fmaf(a[1], s0.y, h0.y), 0.f);
      a[2] = fmaxf(fmaf(a[2], s0.z, h0.z), 0.f);
      a[3] = fmaxf(fmaf(a[3], s0.w, h0.w), 0.f);
      a[4] = fmaxf(fmaf(a[4], s1.x, h1.x), 0.f);
      a[5] = fmaxf(fmaf(a[5], s1.y, h1.y), 0.f);
      a[6] = fmaxf(fmaf(a[6], s1.z, h1.z), 0.f);
      a[7] = fmaxf(fmaf(a[7], s1.w, h1.w), 0.f);
    }
    sv8 ahi, alo;
#pragma unroll
    for (int j = 0; j < 8; ++j) {
      unsigned short h = f2bf(a[j]);
      ahi[j] = (short)h;
      alo[j] = (short)f2bf(a[j] - bf2f(h));
    }
#pragma unroll
    for (int nt = 0; nt < 8; ++nt) {
      sv8 bh = bsh[kc * 512 + nt * 64 + lane];
      sv8 bl = bsl[kc * 512 + nt * 64 + lane];
      acc[nt] = __builtin_amdgcn_mfma_f32_16x16x32_bf16(ahi, bh, acc[nt], 0, 0, 0);
      acc[nt] = __builtin_amdgcn_mfma_f32_16x16x32_bf16(alo, bh, acc[nt], 0, 0, 0);
      acc[nt] = __builtin_amdgcn_mfma_f32_16x16x32_bf16(ahi, bl, acc[nt], 0, 0, 0);
    }
  }
  // ---- epilogue: C/D layout col=nt*16+c, row=wave*16+q*4+reg ----
#pragma unroll
  for (int nt = 0; nt < 8; ++nt) {
    int colg = nt * 16 + c;
#pragma unroll
    for (int reg = 0; reg < 4; ++reg) {
      int g = t * 64 + wave * 16 + q * 4 + reg;
      if (g < n) {
        float v = acc[nt][reg] + bv[nt];
        if (OUT_BF16)
          outb[(size_t)g * 128 + colg] = f2bf(v);
        else
          outf[(size_t)g * 128 + colg] = v;
      }
    }
  }
}

// ---------------- launch ----------------
extern "C" void kernel_launch(void* const* d_in, const int* in_sizes, int n_in,
                              void* d_out, int out_size, void* d_ws, size_t ws_size,
                              hipStream_t stream) {
  const float* x   = (const float*)d_in[0];
  const int*   ei  = (const int*)d_in[1];
  const float* eps = (const float*)d_in[2];
  const float* W1  = (const float*)d_in[3];
  const float* b1  = (const float*)d_in[4];
  const float* g1  = (const float*)d_in[5];
  const float* be1 = (const float*)d_in[6];
  const float* W2  = (const float*)d_in[7];
  const float* b2  = (const float*)d_in[8];
  const float* bng = (const float*)d_in[9];
  const float* bnb = (const float*)d_in[10];
  int n = in_sizes[0] / 128;
  int E = in_sizes[1] / 2;

  char* ws = (char*)d_ws;
  size_t off = 0;
  auto alloc = [&](size_t bytes) -> void* {
    void* p = ws + off;
    off += (bytes + 255) & ~(size_t)255;
    return p;
  };
  // cnt and ST first + adjacent -> single zeroing range covers both
  int*   cnt  = (int*)alloc((size_t)(n + 1) * 4);   // cnt[n] + ocnt
  int*   ocnt = cnt + n;
  float* ST   = (float*)alloc((size_t)5 * REP * 256 * 4);  // 5 pairs x REP x (sum|sq)
  int zwords = (int)(((char*)(ST + (size_t)5 * REP * 256) - (char*)cnt) / 4);
  int*   ovf  = (int*)alloc((size_t)MAXOVF * 2 * 4);
  unsigned short* ell = (unsigned short*)alloc((size_t)n * ELLK * 2);
  float* agg  = (float*)alloc((size_t)n * 128 * 4);
  float* y1   = (float*)alloc((size_t)n * 128 * 4);
  unsigned short* y2b = (unsigned short*)alloc((size_t)n * 128 * 2);
  unsigned short* xbf = (unsigned short*)alloc((size_t)n * 128 * 2);
  unsigned short* wbh = (unsigned short*)alloc(6 * 16384 * 2);
  unsigned short* wbl = (unsigned short*)alloc(6 * 16384 * 2);
  int nb = (E + 1023) / 1024;
  int chunk = (E + nb - 1) / nb;           // <= 1024 by construction
  unsigned* seg = (unsigned*)alloc((size_t)nb * chunk * 4);
  int* lens = (int*)alloc((size_t)nb * 8 * 4);

  // prep first: zeroes cnt+ocnt+ST (blocks 48..111), W fragments, x bf16 cast
  int total4 = n * 32;
  k_prep<<<48 + ZBLK + (total4 + 255) / 256, 256, 0, stream>>>(
      x, xbf, total4, W1, W2, wbh, wbl, cnt, zwords);
  // two-phase ELL build: class-sorted private segments -> per-partition LDS assembly
  k_bucket<<<nb, 256, 0, stream>>>(ei, seg, lens, E, chunk);
  int nparts = (n + P2N - 1) / P2N;
  k_build<<<nparts, 256, 0, stream>>>(seg, lens, cnt, ell, ovf, ocnt, nb, chunk, n);

  int ntiles = (n + 63) / 64;
  int gatherb = 2048;
  int statb = 512;
  float inv_n = 1.0f / (float)n;
  for (int l = 0; l < 3; ++l) {
    float* stA = ST + (size_t)(l * 2) * REP * 256;
    float* stB = ST + (size_t)(l * 2 + 1) * REP * 256;
    const unsigned short* w1h = wbh + (size_t)l * 16384;
    const unsigned short* w1l = wbl + (size_t)l * 16384;
    const unsigned short* w2h = wbh + (size_t)(3 + l) * 16384;
    const unsigned short* w2l = wbl + (size_t)(3 + l) * 16384;
    // 1) aggregation (folds previous inter-layer BN+ReLU for l>0), bf16 + ELL
    if (l == 0) {
      k_gather<false><<<gatherb, 256, 0, stream>>>(
          xbf, nullptr, nullptr, nullptr, inv_n, cnt, ell, ovf, ocnt, eps, l, agg, n);
    } else {
      float* stPrev = ST + (size_t)((l - 1) * 2 + 1) * REP * 256;
      k_gather<true><<<gatherb, 256, 0, stream>>>(
          y2b, stPrev, bng + (size_t)(l - 1) * 128, bnb + (size_t)(l - 1) * 128, inv_n,
          cnt, ell, ovf, ocnt, eps, l, agg, n);
    }
    // 2) GEMM1 + bias (pure) -> y1 fp32
    k_gemm_mfma<false, false><<<ntiles, 256, 0, stream>>>(
        agg, nullptr, nullptr, nullptr, inv_n, w1h, w1l, b1 + (size_t)l * 128,
        y1, nullptr, n);
    // 3) column stats of y1 -> stA
    k_stats<false><<<statb, 256, 0, stream>>>(y1, stA, n);
    // 4) GEMM2 with in-prologue BN finalize + BN+ReLU on load
    if (l < 2) {
      k_gemm_mfma<true, true><<<ntiles, 256, 0, stream>>>(
          y1, stA, g1 + (size_t)l * 128, be1 + (size_t)l * 128, inv_n,
          w2h, w2l, b2 + (size_t)l * 128, nullptr, y2b, n);
      // 5) column stats of y2 (bf16) -> stB
      k_stats<true><<<statb, 256, 0, stream>>>(y2b, stB, n);
    } else {
      k_gemm_mfma<true, false><<<ntiles, 256, 0, stream>>>(
          y1, stA, g1 + (size_t)l * 128, be1 + (size_t)l * 128, inv_n,
          w2h, w2l, b2 + (size_t)l * 128, (float*)d_out, nullptr, n);
    }
  }
}

// Round 12
// 373.831 us; speedup vs baseline: 1.4125x; 1.4125x over previous
//
#include <hip/hip_runtime.h>
#include <stddef.h>

#define TBN_EPS 1e-5f
#define ELLK 32          // Poisson(16): P(deg>32)~1.4e-4 -> ~7 nodes overflow
#define MAXOVF 4096
#define PSH 8            // 256-node partitions (np = ceil(n/256) <= 256 since n <= 65536)
#define P2N 256
#define REP 16           // stat replica slots

typedef short sv8 __attribute__((ext_vector_type(8)));     // 8 bf16 (4 VGPRs)
typedef float fv4 __attribute__((ext_vector_type(4)));     // MFMA C/D

__device__ inline unsigned short f2bf(float f) {  // RNE float -> bf16 bits
  unsigned u = __float_as_uint(f);
  u += 0x7FFF + ((u >> 16) & 1);
  return (unsigned short)(u >> 16);
}
__device__ inline float bf2f(unsigned short h) {
  return __uint_as_float(((unsigned)h) << 16);
}

// ---------------- phase 1: partition-sort private edge chunks ----------------
// Each block owns a contiguous chunk of <=1024 edges, sorts them by PARTITION
// (dst>>PSH, np bins) in LDS, writes one packed (src | dlocal<<16) segment to a
// private region (coalesced) + per-partition {len, off} tables. Zero scattered
// global writes; edge list read exactly once.
__global__ __launch_bounds__(256) void k_bucket(
    const int* __restrict__ ei, unsigned* __restrict__ seg,
    int* __restrict__ lens, int* __restrict__ offs, int E, int chunk, int np) {
  __shared__ int s_nz;
  __shared__ int s_cnt[256], s_pos[256];
  __shared__ unsigned s_buf[1024];
  int b = blockIdx.x, tid = threadIdx.x;
  if (tid == 0) s_nz = 0;
  for (int i = tid; i < np; i += 256) s_cnt[i] = 0;
  __syncthreads();
  {
    int idx = 2 * tid + 1;
    int v = (idx < E) ? ei[idx] : 0;   // odd dwords: i64 high-halves (all 0) vs i32 payload
    if (v != 0) atomicOr(&s_nz, 1);
  }
  __syncthreads();
  bool i64 = (s_nz == 0);
  const int2* ei64s = (const int2*)ei;
  const int2* ei64d = (const int2*)(ei + 2 * (size_t)E);
  int e0 = b * chunk;
  int ecnt = E - e0;
  ecnt = (ecnt < chunk) ? ecnt : chunk;
  if (ecnt < 0) ecnt = 0;
  unsigned pk[4];
  int part[4];
  int nk = 0;
  for (int i = tid; i < ecnt; i += 256, ++nk) {
    int e = e0 + i;
    int d = i64 ? ei64d[e].x : ei[(size_t)E + e];
    int s = i64 ? ei64s[e].x : ei[e];
    pk[nk] = (unsigned)(s & 0xFFFF) | ((unsigned)(d & (P2N - 1)) << 16);
    part[nk] = d >> PSH;
    atomicAdd(&s_cnt[part[nk]], 1);
  }
  __syncthreads();
  if (tid == 0) {
    int acc = 0;
    for (int c = 0; c < np; ++c) { s_pos[c] = acc; acc += s_cnt[c]; }
  }
  __syncthreads();
  // emit tables BEFORE the scatter mutates s_pos
  for (int i = tid; i < np; i += 256) {
    lens[(size_t)b * np + i] = s_cnt[i];
    offs[(size_t)b * np + i] = s_pos[i];
  }
  __syncthreads();
  for (int k = 0; k < nk; ++k) {
    int p = atomicAdd(&s_pos[part[k]], 1);
    s_buf[p] = pk[k];
  }
  __syncthreads();
  unsigned* out = seg + (size_t)b * chunk;
  for (int i = tid; i < ecnt; i += 256) out[i] = s_buf[i];
}

// ---------------- phase 2: per-partition LDS ELL assembly ----------------
// One block per 256-node partition. Threads stripe over chunk-segments and read
// ONLY this partition's slice via {off,len} — total scan work = E exactly.
// Same-row stores are LDS; ELL slice written as one coalesced 16KB burst.
__global__ __launch_bounds__(256) void k_build(
    const unsigned* __restrict__ seg, const int* __restrict__ lens,
    const int* __restrict__ offs, int* __restrict__ cnt,
    unsigned short* __restrict__ ell, int* __restrict__ ovf, int* __restrict__ ocnt,
    int nb, int chunk, int n, int np) {
  __shared__ unsigned short s_ell[P2N * ELLK];   // 16 KB
  __shared__ int s_cnt[P2N];                     // 1 KB
  int p = blockIdx.x, tid = threadIdx.x;
  int node0 = p << PSH;
  for (int i = tid; i < P2N; i += 256) s_cnt[i] = 0;
  __syncthreads();
  for (int b = tid; b < nb; b += 256) {
    int len = lens[(size_t)b * np + p];
    int off = offs[(size_t)b * np + p];
    const unsigned* sp = seg + (size_t)b * chunk + off;
    for (int i = 0; i < len; ++i) {
      unsigned pkv = sp[i];
      int dl = (int)(pkv >> 16);
      int pos = atomicAdd(&s_cnt[dl], 1);
      if (pos < ELLK) {
        s_ell[dl * ELLK + pos] = (unsigned short)(pkv & 0xFFFF);
      } else {
        int o = atomicAdd(ocnt, 1);
        if (o < MAXOVF) { ovf[2 * o] = (int)(pkv & 0xFFFF); ovf[2 * o + 1] = node0 + dl; }
      }
    }
  }
  __syncthreads();
  int rows = n - node0;
  rows = (rows < P2N) ? rows : P2N;
  if (rows <= 0) return;
  for (int i = tid; i < rows; i += 256) cnt[node0 + i] = s_cnt[i];
  int tot16 = rows * 4;   // rows * 64B as uint4
  const uint4* src4 = (const uint4*)s_ell;
  uint4* dst4 = (uint4*)(ell + (size_t)node0 * ELLK);
  for (int i = tid; i < tot16; i += 256) dst4[i] = src4[i];
}

// ------- merged: workspace zeroing + W -> MFMA fragments + x fp32->bf16 cast -------
#define ZBLK 64
__global__ __launch_bounds__(256) void k_prep(
    const float* __restrict__ x, unsigned short* __restrict__ xb, int total4,
    const float* __restrict__ W1, const float* __restrict__ W2,
    unsigned short* __restrict__ wbh, unsigned short* __restrict__ wbl,
    int* __restrict__ zbase, int zwords) {
  int b = blockIdx.x;
  if (b < 48) {  // W prep: 48 blocks = 8 x 3 layers x 2 matrices
    int bz = b / 24, by = (b % 24) / 8, bx = b % 8;
    int ent = bx * 256 + threadIdx.x;   // (kc*8+nt)*64+lane
    int lane = ent & 63;
    int t = ent >> 6;
    int nt = t & 7;
    int kc = t >> 3;
    const float* W = (bz ? W2 : W1) + (size_t)by * 16384;
    size_t mbase = (size_t)(bz * 3 + by) * 16384;
    int q = lane >> 4, cc = lane & 15;
    int col = nt * 16 + cc;
    size_t obase = mbase + (size_t)ent * 8;
#pragma unroll
    for (int j = 0; j < 8; ++j) {
      float w = W[(size_t)(kc * 32 + q * 8 + j) * 128 + col];
      unsigned short h = f2bf(w);
      unsigned short l = f2bf(w - bf2f(h));
      wbh[obase + j] = h;
      wbl[obase + j] = l;
    }
  } else if (b < 48 + ZBLK) {  // zero cnt + ocnt + ST
    int i = (b - 48) * 256 + threadIdx.x;
    int stride = ZBLK * 256;
    for (; i < zwords; i += stride) zbase[i] = 0;
  } else {
    int i = (b - 48 - ZBLK) * 256 + threadIdx.x;
    if (i < total4) {
      float4 v = ((const float4*)x)[i];
      ushort4 o;
      o.x = f2bf(v.x); o.y = f2bf(v.y); o.z = f2bf(v.z); o.w = f2bf(v.w);
      ((ushort4*)xb)[i] = o;
    }
  }
}

// ---------------- gather: agg = (1+eps)*f(x[g]) + sum f(x[src]), bf16 + ELL -------
// Wave-uniform scalar index loads; overflow rows scan the tiny ovf list inline.
template <bool BN>
__global__ __launch_bounds__(256, 8) void k_gather(
    const unsigned short* __restrict__ xin, const float* __restrict__ stats,
    const float* __restrict__ gamma, const float* __restrict__ beta, float inv_n,
    const int* __restrict__ cnt, const unsigned short* __restrict__ ell,
    const int* __restrict__ ovf, const int* __restrict__ ocnt,
    const float* __restrict__ eps_arr, int layer, float* __restrict__ agg, int n) {
  __shared__ float s_sc[128], s_sh[128];
  if (BN) {
    int i = threadIdx.x;
    if (i < 128) {
      float s = 0.f, q = 0.f;
#pragma unroll
      for (int r = 0; r < REP; ++r) { s += stats[r * 256 + i]; q += stats[r * 256 + 128 + i]; }
      float m = s * inv_n;
      float var = q * inv_n - m * m;
      float scale = rsqrtf(var + TBN_EPS) * gamma[i];
      s_sc[i] = scale;
      s_sh[i] = beta[i] - m * scale;
    }
    __syncthreads();
  }
  int lane = threadIdx.x & 63;
  int wid = blockIdx.x * (blockDim.x >> 6) + (threadIdx.x >> 6);
  int nw = gridDim.x * (blockDim.x >> 6);
  float ep = 1.0f + eps_arr[layer];
  float sc0 = 1.f, sh0 = 0.f, sc1 = 1.f, sh1 = 0.f;
  if (BN) {
    float2 s2 = ((const float2*)s_sc)[lane];
    float2 h2 = ((const float2*)s_sh)[lane];
    sc0 = s2.x; sc1 = s2.y; sh0 = h2.x; sh1 = h2.y;
  }
  const unsigned* xb = (const unsigned*)xin;  // one dword = 2 bf16 cols
  for (int g = wid; g < n; g += nw) {
    int deg0 = cnt[g];
    int deg = (deg0 < ELLK) ? deg0 : ELLK;
    const unsigned short* row = ell + (size_t)g * ELLK;
    unsigned r = xb[(size_t)g * 64 + lane];
    float vx = __uint_as_float(r << 16);
    float vy = __uint_as_float(r & 0xFFFF0000u);
    if (BN) {
      vx = fmaxf(fmaf(vx, sc0, sh0), 0.f);
      vy = fmaxf(fmaf(vy, sc1, sh1), 0.f);
    }
    float ax = ep * vx, ay = ep * vy;
    int j = 0;
    for (; j + 7 < deg; j += 8) {
      unsigned rr[8];
#pragma unroll
      for (int jj = 0; jj < 8; ++jj) rr[jj] = xb[(size_t)row[j + jj] * 64 + lane];
#pragma unroll
      for (int jj = 0; jj < 8; ++jj) {
        float xv = __uint_as_float(rr[jj] << 16);
        float yv = __uint_as_float(rr[jj] & 0xFFFF0000u);
        if (BN) {
          xv = fmaxf(fmaf(xv, sc0, sh0), 0.f);
          yv = fmaxf(fmaf(yv, sc1, sh1), 0.f);
        }
        ax += xv; ay += yv;
      }
    }
    for (; j + 3 < deg; j += 4) {
      unsigned rr[4];
#pragma unroll
      for (int jj = 0; jj < 4; ++jj) rr[jj] = xb[(size_t)row[j + jj] * 64 + lane];
#pragma unroll
      for (int jj = 0; jj < 4; ++jj) {
        float xv = __uint_as_float(rr[jj] << 16);
        float yv = __uint_as_float(rr[jj] & 0xFFFF0000u);
        if (BN) {
          xv = fmaxf(fmaf(xv, sc0, sh0), 0.f);
          yv = fmaxf(fmaf(yv, sc1, sh1), 0.f);
        }
        ax += xv; ay += yv;
      }
    }
    for (; j < deg; ++j) {
      unsigned r0 = xb[(size_t)row[j] * 64 + lane];
      float x0 = __uint_as_float(r0 << 16), y0 = __uint_as_float(r0 & 0xFFFF0000u);
      if (BN) {
        x0 = fmaxf(fmaf(x0, sc0, sh0), 0.f);
        y0 = fmaxf(fmaf(y0, sc1, sh1), 0.f);
      }
      ax += x0; ay += y0;
    }
    if (deg0 > ELLK) {  // rare: scan tiny overflow list for this dst
      int oc = *ocnt;
      oc = (oc < MAXOVF) ? oc : MAXOVF;
      for (int i = 0; i < oc; ++i) {
        if (ovf[2 * i + 1] == g) {
          unsigned r0 = xb[(size_t)ovf[2 * i] * 64 + lane];
          float x0 = __uint_as_float(r0 << 16), y0 = __uint_as_float(r0 & 0xFFFF0000u);
          if (BN) {
            x0 = fmaxf(fmaf(x0, sc0, sh0), 0.f);
            y0 = fmaxf(fmaf(y0, sc1, sh1), 0.f);
          }
          ax += x0; ay += y0;
        }
      }
    }
    ((float2*)agg)[(size_t)g * 64 + lane] = make_float2(ax, ay);
  }
}

// ---------------- column stats: sum / sumsq per column -> REP-replicated table ----
template <bool BF16IN>
__global__ __launch_bounds__(256) void k_stats(
    const void* __restrict__ in, float* __restrict__ st, int n) {
  __shared__ float sm_sum[4][128], sm_sq[4][128];
  int tid = threadIdx.x;
  int c = tid & 63;       // handles cols 2c, 2c+1
  int rg = tid >> 6;      // 4 row-groups
  float s0 = 0.f, s1 = 0.f, q0 = 0.f, q1 = 0.f;
  for (int r = blockIdx.x * 4 + rg; r < n; r += gridDim.x * 4) {
    float a, b;
    if (BF16IN) {
      unsigned v = ((const unsigned*)in)[(size_t)r * 64 + c];
      a = __uint_as_float(v << 16);
      b = __uint_as_float(v & 0xFFFF0000u);
    } else {
      float2 v = ((const float2*)in)[(size_t)r * 64 + c];
      a = v.x; b = v.y;
    }
    s0 += a; s1 += b; q0 += a * a; q1 += b * b;
  }
  sm_sum[rg][2 * c] = s0; sm_sum[rg][2 * c + 1] = s1;
  sm_sq[rg][2 * c] = q0;  sm_sq[rg][2 * c + 1] = q1;
  __syncthreads();
  if (tid < 128) {
    float s = 0.f, q = 0.f;
#pragma unroll
    for (int g = 0; g < 4; ++g) { s += sm_sum[g][tid]; q += sm_sq[g][tid]; }
    float* base = st + (size_t)(blockIdx.x & (REP - 1)) * 256;
    atomicAdd(&base[tid], s);
    atomicAdd(&base[128 + tid], q);
  }
}

// ---------------- pure MFMA GEMM: one 64-row tile per block, B in LDS ----------------
// out = f(in) @ W + bias. bf16x3 split product. No stats, no atomics.
template <bool BN_IN, bool OUT_BF16>
__global__ __launch_bounds__(256) void k_gemm_mfma(
    const float* __restrict__ in, const float* __restrict__ bn_stats,
    const float* __restrict__ bn_gamma, const float* __restrict__ bn_beta, float inv_n,
    const unsigned short* __restrict__ wh, const unsigned short* __restrict__ wl,
    const float* __restrict__ bias, float* __restrict__ outf,
    unsigned short* __restrict__ outb, int n) {
  __shared__ unsigned short Bs[32768];   // 64 KB: [0..2047]=hi sv8, [2048..4095]=lo
  __shared__ float s_sc[128], s_sh[128];
  int tid = threadIdx.x;
  int wave = tid >> 6, lane = tid & 63;
  int q = lane >> 4, c = lane & 15;
  int t = blockIdx.x;
  int row = t * 64 + wave * 16 + c;
  bool valid = row < n;
  // A loads issued first — latency hides under B staging
  float4 va[8];
#pragma unroll
  for (int kc = 0; kc < 4; ++kc) {
    va[kc * 2] = make_float4(0.f, 0.f, 0.f, 0.f);
    va[kc * 2 + 1] = make_float4(0.f, 0.f, 0.f, 0.f);
    if (valid) {
      const float* p = &in[(size_t)row * 128 + kc * 32 + q * 8];
      va[kc * 2] = *(const float4*)p;
      va[kc * 2 + 1] = *(const float4*)(p + 4);
    }
  }
  // bulk cooperative B stage (pipelined 16B loads)
  {
    const sv8* whv = (const sv8*)wh;
    const sv8* wlv = (const sv8*)wl;
    sv8* bs = (sv8*)Bs;
#pragma unroll
    for (int r = 0; r < 8; ++r) {
      bs[tid + 256 * r] = whv[tid + 256 * r];
      bs[2048 + tid + 256 * r] = wlv[tid + 256 * r];
    }
  }
  if (BN_IN && tid < 128) {
    float s = 0.f, qq = 0.f;
#pragma unroll
    for (int r = 0; r < REP; ++r) { s += bn_stats[r * 256 + tid]; qq += bn_stats[r * 256 + 128 + tid]; }
    float m = s * inv_n;
    float var = qq * inv_n - m * m;
    float scale = rsqrtf(var + TBN_EPS) * bn_gamma[tid];
    s_sc[tid] = scale;
    s_sh[tid] = bn_beta[tid] - m * scale;
  }
  float bv[8];
#pragma unroll
  for (int nt = 0; nt < 8; ++nt) bv[nt] = bias[nt * 16 + c];
  const sv8* bsh = (const sv8*)Bs;
  const sv8* bsl = ((const sv8*)Bs) + 2048;
  __syncthreads();
  fv4 acc[8];
#pragma unroll
  for (int nt = 0; nt < 8; ++nt) acc[nt] = (fv4){0.f, 0.f, 0.f, 0.f};
#pragma unroll
  for (int kc = 0; kc < 4; ++kc) {
    float a[8];
    a[0] = va[kc * 2].x; a[1] = va[kc * 2].y; a[2] = va[kc * 2].z; a[3] = va[kc * 2].w;
    a[4] = va[kc * 2 + 1].x; a[5] = va[kc * 2 + 1].y;
    a[6] = va[kc * 2 + 1].z; a[7] = va[kc * 2 + 1].w;
    if (BN_IN) {
      const float4 s0 = *(const float4*)&s_sc[kc * 32 + q * 8];
      const float4 s1 = *(const float4*)&s_sc[kc * 32 + q * 8 + 4];
      const float4 h0 = *(const float4*)&s_sh[kc * 32 + q * 8];
      const float4 h1 = *(const float4*)&s_sh[kc * 32 + q * 8 + 4];
      a[0] = fmaxf(fmaf(a[0], s0.x, h0.x), 0.f);
      a[1] = fmaxf(fmaf(a[1], s0.y, h0.y), 0.f);
      a[2] = fmaxf(fmaf(a[2], s0.z, h0.z), 0.f);
      a[3] = fmaxf(fmaf(a[3], s0.w, h0.w), 0.f);
      a[4] = fmaxf(fmaf(a[4], s1.x, h1.x), 0.f);
      a[5] = fmaxf(fmaf(a[5], s1.y, h1.y), 0.f);
      a[6] = fmaxf(fmaf(a[6], s1.z, h1.z), 0.f);
      a[7] = fmaxf(fmaf(a[7], s1.w, h1.w), 0.f);
    }
    sv8 ahi, alo;
#pragma unroll
    for (int j = 0; j < 8; ++j) {
      unsigned short h = f2bf(a[j]);
      ahi[j] = (short)h;
      alo[j] = (short)f2bf(a[j] - bf2f(h));
    }
#pragma unroll
    for (int nt = 0; nt < 8; ++nt) {
      sv8 bh = bsh[kc * 512 + nt * 64 + lane];
      sv8 bl = bsl[kc * 512 + nt * 64 + lane];
      acc[nt] = __builtin_amdgcn_mfma_f32_16x16x32_bf16(ahi, bh, acc[nt], 0, 0, 0);
      acc[nt] = __builtin_amdgcn_mfma_f32_16x16x32_bf16(alo, bh, acc[nt], 0, 0, 0);
      acc[nt] = __builtin_amdgcn_mfma_f32_16x16x32_bf16(ahi, bl, acc[nt], 0, 0, 0);
    }
  }
  // ---- epilogue: C/D layout col=nt*16+c, row=wave*16+q*4+reg ----
#pragma unroll
  for (int nt = 0; nt < 8; ++nt) {
    int colg = nt * 16 + c;
#pragma unroll
    for (int reg = 0; reg < 4; ++reg) {
      int g = t * 64 + wave * 16 + q * 4 + reg;
      if (g < n) {
        float v = acc[nt][reg] + bv[nt];
        if (OUT_BF16)
          outb[(size_t)g * 128 + colg] = f2bf(v);
        else
          outf[(size_t)g * 128 + colg] = v;
      }
    }
  }
}

// ---------------- launch ----------------
extern "C" void kernel_launch(void* const* d_in, const int* in_sizes, int n_in,
                              void* d_out, int out_size, void* d_ws, size_t ws_size,
                              hipStream_t stream) {
  const float* x   = (const float*)d_in[0];
  const int*   ei  = (const int*)d_in[1];
  const float* eps = (const float*)d_in[2];
  const float* W1  = (const float*)d_in[3];
  const float* b1  = (const float*)d_in[4];
  const float* g1  = (const float*)d_in[5];
  const float* be1 = (const float*)d_in[6];
  const float* W2  = (const float*)d_in[7];
  const float* b2  = (const float*)d_in[8];
  const float* bng = (const float*)d_in[9];
  const float* bnb = (const float*)d_in[10];
  int n = in_sizes[0] / 128;
  int E = in_sizes[1] / 2;

  char* ws = (char*)d_ws;
  size_t off = 0;
  auto alloc = [&](size_t bytes) -> void* {
    void* p = ws + off;
    off += (bytes + 255) & ~(size_t)255;
    return p;
  };
  // cnt and ST first + adjacent -> single zeroing range covers both
  int*   cnt  = (int*)alloc((size_t)(n + 1) * 4);   // cnt[n] + ocnt
  int*   ocnt = cnt + n;
  float* ST   = (float*)alloc((size_t)5 * REP * 256 * 4);  // 5 pairs x REP x (sum|sq)
  int zwords = (int)(((char*)(ST + (size_t)5 * REP * 256) - (char*)cnt) / 4);
  int*   ovf  = (int*)alloc((size_t)MAXOVF * 2 * 4);
  unsigned short* ell = (unsigned short*)alloc((size_t)n * ELLK * 2);
  float* agg  = (float*)alloc((size_t)n * 128 * 4);
  float* y1   = (float*)alloc((size_t)n * 128 * 4);
  unsigned short* y2b = (unsigned short*)alloc((size_t)n * 128 * 2);
  unsigned short* xbf = (unsigned short*)alloc((size_t)n * 128 * 2);
  unsigned short* wbh = (unsigned short*)alloc(6 * 16384 * 2);
  unsigned short* wbl = (unsigned short*)alloc(6 * 16384 * 2);
  int nb = (E + 1023) / 1024;
  int chunk = (E + nb - 1) / nb;           // <= 1024 by construction
  int np = (n + P2N - 1) >> PSH;           // <= 256 (n fits u16)
  unsigned* seg = (unsigned*)alloc((size_t)nb * chunk * 4);
  int* lens = (int*)alloc((size_t)nb * np * 4);
  int* offs = (int*)alloc((size_t)nb * np * 4);

  // prep first: zeroes cnt+ocnt+ST (blocks 48..111), W fragments, x bf16 cast
  int total4 = n * 32;
  k_prep<<<48 + ZBLK + (total4 + 255) / 256, 256, 0, stream>>>(
      x, xbf, total4, W1, W2, wbh, wbl, cnt, zwords);
  // two-phase ELL build: partition-sorted private segments -> per-partition LDS assembly
  k_bucket<<<nb, 256, 0, stream>>>(ei, seg, lens, offs, E, chunk, np);
  k_build<<<np, 256, 0, stream>>>(seg, lens, offs, cnt, ell, ovf, ocnt, nb, chunk, n, np);

  int ntiles = (n + 63) / 64;
  int gatherb = 2048;
  int statb = 512;
  float inv_n = 1.0f / (float)n;
  for (int l = 0; l < 3; ++l) {
    float* stA = ST + (size_t)(l * 2) * REP * 256;
    float* stB = ST + (size_t)(l * 2 + 1) * REP * 256;
    const unsigned short* w1h = wbh + (size_t)l * 16384;
    const unsigned short* w1l = wbl + (size_t)l * 16384;
    const unsigned short* w2h = wbh + (size_t)(3 + l) * 16384;
    const unsigned short* w2l = wbl + (size_t)(3 + l) * 16384;
    // 1) aggregation (folds previous inter-layer BN+ReLU for l>0), bf16 + ELL
    if (l == 0) {
      k_gather<false><<<gatherb, 256, 0, stream>>>(
          xbf, nullptr, nullptr, nullptr, inv_n, cnt, ell, ovf, ocnt, eps, l, agg, n);
    } else {
      float* stPrev = ST + (size_t)((l - 1) * 2 + 1) * REP * 256;
      k_gather<true><<<gatherb, 256, 0, stream>>>(
          y2b, stPrev, bng + (size_t)(l - 1) * 128, bnb + (size_t)(l - 1) * 128, inv_n,
          cnt, ell, ovf, ocnt, eps, l, agg, n);
    }
    // 2) GEMM1 + bias (pure) -> y1 fp32
    k_gemm_mfma<false, false><<<ntiles, 256, 0, stream>>>(
        agg, nullptr, nullptr, nullptr, inv_n, w1h, w1l, b1 + (size_t)l * 128,
        y1, nullptr, n);
    // 3) column stats of y1 -> stA
    k_stats<false><<<statb, 256, 0, stream>>>(y1, stA, n);
    // 4) GEMM2 with in-prologue BN finalize + BN+ReLU on load
    if (l < 2) {
      k_gemm_mfma<true, true><<<ntiles, 256, 0, stream>>>(
          y1, stA, g1 + (size_t)l * 128, be1 + (size_t)l * 128, inv_n,
          w2h, w2l, b2 + (size_t)l * 128, nullptr, y2b, n);
      // 5) column stats of y2 (bf16) -> stB
      k_stats<true><<<statb, 256, 0, stream>>>(y2b, stB, n);
    } else {
      k_gemm_mfma<true, false><<<ntiles, 256, 0, stream>>>(
          y1, stA, g1 + (size_t)l * 128, be1 + (size_t)l * 128, inv_n,
          w2h, w2l, b2 + (size_t)l * 128, (float*)d_out, nullptr, n);
    }
  }
}

// Round 13
// 357.678 us; speedup vs baseline: 1.4763x; 1.0452x over previous
//
#include <hip/hip_runtime.h>
#include <stddef.h>

#define TBN_EPS 1e-5f
#define ELLK 32          // Poisson(16): P(deg>32)~1.4e-4 -> ~7 nodes overflow
#define MAXOVF 4096
#define PSH 8            // 256-node partitions (np = ceil(n/256) <= 256 since n <= 65536)
#define P2N 256
#define REP 16           // stat replica slots

typedef short sv8 __attribute__((ext_vector_type(8)));     // 8 bf16 (4 VGPRs)
typedef float fv4 __attribute__((ext_vector_type(4)));     // MFMA C/D

__device__ inline unsigned short f2bf(float f) {  // RNE float -> bf16 bits
  unsigned u = __float_as_uint(f);
  u += 0x7FFF + ((u >> 16) & 1);
  return (unsigned short)(u >> 16);
}
__device__ inline float bf2f(unsigned short h) {
  return __uint_as_float(((unsigned)h) << 16);
}

// ---------------- phase 1: partition-sort private edge chunks ----------------
__global__ __launch_bounds__(256) void k_bucket(
    const int* __restrict__ ei, unsigned* __restrict__ seg,
    int* __restrict__ lens, int* __restrict__ offs, int E, int chunk, int np) {
  __shared__ int s_nz;
  __shared__ int s_cnt[256], s_pos[256];
  __shared__ unsigned s_buf[1024];
  int b = blockIdx.x, tid = threadIdx.x;
  if (tid == 0) s_nz = 0;
  for (int i = tid; i < np; i += 256) s_cnt[i] = 0;
  __syncthreads();
  {
    int idx = 2 * tid + 1;
    int v = (idx < E) ? ei[idx] : 0;   // odd dwords: i64 high-halves (all 0) vs i32 payload
    if (v != 0) atomicOr(&s_nz, 1);
  }
  __syncthreads();
  bool i64 = (s_nz == 0);
  const int2* ei64s = (const int2*)ei;
  const int2* ei64d = (const int2*)(ei + 2 * (size_t)E);
  int e0 = b * chunk;
  int ecnt = E - e0;
  ecnt = (ecnt < chunk) ? ecnt : chunk;
  if (ecnt < 0) ecnt = 0;
  unsigned pk[4];
  int part[4];
  int nk = 0;
  for (int i = tid; i < ecnt; i += 256, ++nk) {
    int e = e0 + i;
    int d = i64 ? ei64d[e].x : ei[(size_t)E + e];
    int s = i64 ? ei64s[e].x : ei[e];
    pk[nk] = (unsigned)(s & 0xFFFF) | ((unsigned)(d & (P2N - 1)) << 16);
    part[nk] = d >> PSH;
    atomicAdd(&s_cnt[part[nk]], 1);
  }
  __syncthreads();
  if (tid == 0) {
    int acc = 0;
    for (int c = 0; c < np; ++c) { s_pos[c] = acc; acc += s_cnt[c]; }
  }
  __syncthreads();
  // emit tables BEFORE the scatter mutates s_pos
  for (int i = tid; i < np; i += 256) {
    lens[(size_t)b * np + i] = s_cnt[i];
    offs[(size_t)b * np + i] = s_pos[i];
  }
  __syncthreads();
  for (int k = 0; k < nk; ++k) {
    int p = atomicAdd(&s_pos[part[k]], 1);
    s_buf[p] = pk[k];
  }
  __syncthreads();
  unsigned* out = seg + (size_t)b * chunk;
  for (int i = tid; i < ecnt; i += 256) out[i] = s_buf[i];
}

// ---------------- phase 2: per-partition LDS ELL assembly ----------------
__global__ __launch_bounds__(256) void k_build(
    const unsigned* __restrict__ seg, const int* __restrict__ lens,
    const int* __restrict__ offs, int* __restrict__ cnt,
    unsigned short* __restrict__ ell, int* __restrict__ ovf, int* __restrict__ ocnt,
    int nb, int chunk, int n, int np) {
  __shared__ unsigned short s_ell[P2N * ELLK];   // 16 KB
  __shared__ int s_cnt[P2N];                     // 1 KB
  int p = blockIdx.x, tid = threadIdx.x;
  int node0 = p << PSH;
  for (int i = tid; i < P2N; i += 256) s_cnt[i] = 0;
  __syncthreads();
  for (int b = tid; b < nb; b += 256) {
    int len = lens[(size_t)b * np + p];
    int off = offs[(size_t)b * np + p];
    const unsigned* sp = seg + (size_t)b * chunk + off;
    for (int i = 0; i < len; ++i) {
      unsigned pkv = sp[i];
      int dl = (int)(pkv >> 16);
      int pos = atomicAdd(&s_cnt[dl], 1);
      if (pos < ELLK) {
        s_ell[dl * ELLK + pos] = (unsigned short)(pkv & 0xFFFF);
      } else {
        int o = atomicAdd(ocnt, 1);
        if (o < MAXOVF) { ovf[2 * o] = (int)(pkv & 0xFFFF); ovf[2 * o + 1] = node0 + dl; }
      }
    }
  }
  __syncthreads();
  int rows = n - node0;
  rows = (rows < P2N) ? rows : P2N;
  if (rows <= 0) return;
  for (int i = tid; i < rows; i += 256) cnt[node0 + i] = s_cnt[i];
  int tot16 = rows * 4;   // rows * 64B as uint4
  const uint4* src4 = (const uint4*)s_ell;
  uint4* dst4 = (uint4*)(ell + (size_t)node0 * ELLK);
  for (int i = tid; i < tot16; i += 256) dst4[i] = src4[i];
}

// ------- merged: workspace zeroing + W -> MFMA fragments + x fp32->bf16 cast -------
#define ZBLK 64
__global__ __launch_bounds__(256) void k_prep(
    const float* __restrict__ x, unsigned short* __restrict__ xb, int total4,
    const float* __restrict__ W1, const float* __restrict__ W2,
    unsigned short* __restrict__ wbh, unsigned short* __restrict__ wbl,
    int* __restrict__ zbase, int zwords) {
  int b = blockIdx.x;
  if (b < 48) {  // W prep: 48 blocks = 8 x 3 layers x 2 matrices
    int bz = b / 24, by = (b % 24) / 8, bx = b % 8;
    int ent = bx * 256 + threadIdx.x;   // (kc*8+nt)*64+lane
    int lane = ent & 63;
    int t = ent >> 6;
    int nt = t & 7;
    int kc = t >> 3;
    const float* W = (bz ? W2 : W1) + (size_t)by * 16384;
    size_t mbase = (size_t)(bz * 3 + by) * 16384;
    int q = lane >> 4, cc = lane & 15;
    int col = nt * 16 + cc;
    size_t obase = mbase + (size_t)ent * 8;
#pragma unroll
    for (int j = 0; j < 8; ++j) {
      float w = W[(size_t)(kc * 32 + q * 8 + j) * 128 + col];
      unsigned short h = f2bf(w);
      unsigned short l = f2bf(w - bf2f(h));
      wbh[obase + j] = h;
      wbl[obase + j] = l;
    }
  } else if (b < 48 + ZBLK) {  // zero cnt + ocnt + ST
    int i = (b - 48) * 256 + threadIdx.x;
    int stride = ZBLK * 256;
    for (; i < zwords; i += stride) zbase[i] = 0;
  } else {
    int i = (b - 48 - ZBLK) * 256 + threadIdx.x;
    if (i < total4) {
      float4 v = ((const float4*)x)[i];
      ushort4 o;
      o.x = f2bf(v.x); o.y = f2bf(v.y); o.z = f2bf(v.z); o.w = f2bf(v.w);
      ((ushort4*)xb)[i] = o;
    }
  }
}

// ---------------- gather: agg = (1+eps)*f(x[g]) + sum f(x[src]), bf16 + ELL -------
template <bool BN>
__global__ __launch_bounds__(256, 8) void k_gather(
    const unsigned short* __restrict__ xin, const float* __restrict__ stats,
    const float* __restrict__ gamma, const float* __restrict__ beta, float inv_n,
    const int* __restrict__ cnt, const unsigned short* __restrict__ ell,
    const int* __restrict__ ovf, const int* __restrict__ ocnt,
    const float* __restrict__ eps_arr, int layer, float* __restrict__ agg, int n) {
  __shared__ float s_sc[128], s_sh[128];
  if (BN) {
    int i = threadIdx.x;
    if (i < 128) {
      float s = 0.f, q = 0.f;
#pragma unroll
      for (int r = 0; r < REP; ++r) { s += stats[r * 256 + i]; q += stats[r * 256 + 128 + i]; }
      float m = s * inv_n;
      float var = q * inv_n - m * m;
      float scale = rsqrtf(var + TBN_EPS) * gamma[i];
      s_sc[i] = scale;
      s_sh[i] = beta[i] - m * scale;
    }
    __syncthreads();
  }
  int lane = threadIdx.x & 63;
  int wid = blockIdx.x * (blockDim.x >> 6) + (threadIdx.x >> 6);
  int nw = gridDim.x * (blockDim.x >> 6);
  float ep = 1.0f + eps_arr[layer];
  float sc0 = 1.f, sh0 = 0.f, sc1 = 1.f, sh1 = 0.f;
  if (BN) {
    float2 s2 = ((const float2*)s_sc)[lane];
    float2 h2 = ((const float2*)s_sh)[lane];
    sc0 = s2.x; sc1 = s2.y; sh0 = h2.x; sh1 = h2.y;
  }
  const unsigned* xb = (const unsigned*)xin;  // one dword = 2 bf16 cols
  for (int g = wid; g < n; g += nw) {
    int deg0 = cnt[g];
    int deg = (deg0 < ELLK) ? deg0 : ELLK;
    const unsigned short* row = ell + (size_t)g * ELLK;
    unsigned r = xb[(size_t)g * 64 + lane];
    float vx = __uint_as_float(r << 16);
    float vy = __uint_as_float(r & 0xFFFF0000u);
    if (BN) {
      vx = fmaxf(fmaf(vx, sc0, sh0), 0.f);
      vy = fmaxf(fmaf(vy, sc1, sh1), 0.f);
    }
    float ax = ep * vx, ay = ep * vy;
    int j = 0;
    for (; j + 7 < deg; j += 8) {
      unsigned rr[8];
#pragma unroll
      for (int jj = 0; jj < 8; ++jj) rr[jj] = xb[(size_t)row[j + jj] * 64 + lane];
#pragma unroll
      for (int jj = 0; jj < 8; ++jj) {
        float xv = __uint_as_float(rr[jj] << 16);
        float yv = __uint_as_float(rr[jj] & 0xFFFF0000u);
        if (BN) {
          xv = fmaxf(fmaf(xv, sc0, sh0), 0.f);
          yv = fmaxf(fmaf(yv, sc1, sh1), 0.f);
        }
        ax += xv; ay += yv;
      }
    }
    for (; j + 3 < deg; j += 4) {
      unsigned rr[4];
#pragma unroll
      for (int jj = 0; jj < 4; ++jj) rr[jj] = xb[(size_t)row[j + jj] * 64 + lane];
#pragma unroll
      for (int jj = 0; jj < 4; ++jj) {
        float xv = __uint_as_float(rr[jj] << 16);
        float yv = __uint_as_float(rr[jj] & 0xFFFF0000u);
        if (BN) {
          xv = fmaxf(fmaf(xv, sc0, sh0), 0.f);
          yv = fmaxf(fmaf(yv, sc1, sh1), 0.f);
        }
        ax += xv; ay += yv;
      }
    }
    for (; j < deg; ++j) {
      unsigned r0 = xb[(size_t)row[j] * 64 + lane];
      float x0 = __uint_as_float(r0 << 16), y0 = __uint_as_float(r0 & 0xFFFF0000u);
      if (BN) {
        x0 = fmaxf(fmaf(x0, sc0, sh0), 0.f);
        y0 = fmaxf(fmaf(y0, sc1, sh1), 0.f);
      }
      ax += x0; ay += y0;
    }
    if (deg0 > ELLK) {  // rare: scan tiny overflow list for this dst
      int oc = *ocnt;
      oc = (oc < MAXOVF) ? oc : MAXOVF;
      for (int i = 0; i < oc; ++i) {
        if (ovf[2 * i + 1] == g) {
          unsigned r0 = xb[(size_t)ovf[2 * i] * 64 + lane];
          float x0 = __uint_as_float(r0 << 16), y0 = __uint_as_float(r0 & 0xFFFF0000u);
          if (BN) {
            x0 = fmaxf(fmaf(x0, sc0, sh0), 0.f);
            y0 = fmaxf(fmaf(y0, sc1, sh1), 0.f);
          }
          ax += x0; ay += y0;
        }
      }
    }
    ((float2*)agg)[(size_t)g * 64 + lane] = make_float2(ax, ay);
  }
}

// ---------------- column stats: sum / sumsq per column -> REP-replicated table ----
template <bool BF16IN>
__global__ __launch_bounds__(256) void k_stats(
    const void* __restrict__ in, float* __restrict__ st, int n) {
  __shared__ float sm_sum[4][128], sm_sq[4][128];
  int tid = threadIdx.x;
  int c = tid & 63;       // handles cols 2c, 2c+1
  int rg = tid >> 6;      // 4 row-groups
  float s0 = 0.f, s1 = 0.f, q0 = 0.f, q1 = 0.f;
  for (int r = blockIdx.x * 4 + rg; r < n; r += gridDim.x * 4) {
    float a, b;
    if (BF16IN) {
      unsigned v = ((const unsigned*)in)[(size_t)r * 64 + c];
      a = __uint_as_float(v << 16);
      b = __uint_as_float(v & 0xFFFF0000u);
    } else {
      float2 v = ((const float2*)in)[(size_t)r * 64 + c];
      a = v.x; b = v.y;
    }
    s0 += a; s1 += b; q0 += a * a; q1 += b * b;
  }
  sm_sum[rg][2 * c] = s0; sm_sum[rg][2 * c + 1] = s1;
  sm_sq[rg][2 * c] = q0;  sm_sq[rg][2 * c + 1] = q1;
  __syncthreads();
  if (tid < 128) {
    float s = 0.f, q = 0.f;
#pragma unroll
    for (int g = 0; g < 4; ++g) { s += sm_sum[g][tid]; q += sm_sq[g][tid]; }
    float* base = st + (size_t)(blockIdx.x & (REP - 1)) * 256;
    atomicAdd(&base[tid], s);
    atomicAdd(&base[128 + tid], q);
  }
}

// ---------------- MFMA GEMM: 128 rows (2 sub-tiles) per block, B in LDS ----------
// out = f(in) @ W + bias. bf16x3 split product. One B-stage serves two 64-row
// sub-tiles: halves B L2-traffic and amortizes the stage->barrier prologue.
// Sub-tile 1's A-loads are issued right after the barrier so they fly under
// sub-tile 0's MFMA chain.
template <bool BN_IN, bool OUT_BF16>
__global__ __launch_bounds__(256) void k_gemm_mfma(
    const float* __restrict__ in, const float* __restrict__ bn_stats,
    const float* __restrict__ bn_gamma, const float* __restrict__ bn_beta, float inv_n,
    const unsigned short* __restrict__ wh, const unsigned short* __restrict__ wl,
    const float* __restrict__ bias, float* __restrict__ outf,
    unsigned short* __restrict__ outb, int n) {
  __shared__ unsigned short Bs[32768];   // 64 KB: [0..2047]=hi sv8, [2048..4095]=lo
  __shared__ float s_sc[128], s_sh[128];
  int tid = threadIdx.x;
  int wave = tid >> 6, lane = tid & 63;
  int q = lane >> 4, c = lane & 15;
  int base = blockIdx.x * 128;
  auto loadA = [&](int row, float4* v) {
    bool valid = row < n;
#pragma unroll
    for (int kc = 0; kc < 4; ++kc) {
      v[kc * 2] = make_float4(0.f, 0.f, 0.f, 0.f);
      v[kc * 2 + 1] = make_float4(0.f, 0.f, 0.f, 0.f);
      if (valid) {
        const float* p = &in[(size_t)row * 128 + kc * 32 + q * 8];
        v[kc * 2] = *(const float4*)p;
        v[kc * 2 + 1] = *(const float4*)(p + 4);
      }
    }
  };
  float4 va0[8], va1[8];
  loadA(base + wave * 16 + c, va0);   // sub-tile 0 A in flight during B stage
  // bulk cooperative B stage (pipelined 16B loads)
  {
    const sv8* whv = (const sv8*)wh;
    const sv8* wlv = (const sv8*)wl;
    sv8* bs = (sv8*)Bs;
#pragma unroll
    for (int r = 0; r < 8; ++r) {
      bs[tid + 256 * r] = whv[tid + 256 * r];
      bs[2048 + tid + 256 * r] = wlv[tid + 256 * r];
    }
  }
  if (BN_IN && tid < 128) {
    float s = 0.f, qq = 0.f;
#pragma unroll
    for (int r = 0; r < REP; ++r) { s += bn_stats[r * 256 + tid]; qq += bn_stats[r * 256 + 128 + tid]; }
    float m = s * inv_n;
    float var = qq * inv_n - m * m;
    float scale = rsqrtf(var + TBN_EPS) * bn_gamma[tid];
    s_sc[tid] = scale;
    s_sh[tid] = bn_beta[tid] - m * scale;
  }
  float bv[8];
#pragma unroll
  for (int nt = 0; nt < 8; ++nt) bv[nt] = bias[nt * 16 + c];
  const sv8* bsh = (const sv8*)Bs;
  const sv8* bsl = ((const sv8*)Bs) + 2048;
  __syncthreads();
  loadA(base + 64 + wave * 16 + c, va1);  // sub-tile 1 A flies under tile-0 MFMA
  auto tile = [&](const float4* va, int tbase) {
    fv4 acc[8];
#pragma unroll
    for (int nt = 0; nt < 8; ++nt) acc[nt] = (fv4){0.f, 0.f, 0.f, 0.f};
#pragma unroll
    for (int kc = 0; kc < 4; ++kc) {
      float a[8];
      a[0] = va[kc * 2].x; a[1] = va[kc * 2].y; a[2] = va[kc * 2].z; a[3] = va[kc * 2].w;
      a[4] = va[kc * 2 + 1].x; a[5] = va[kc * 2 + 1].y;
      a[6] = va[kc * 2 + 1].z; a[7] = va[kc * 2 + 1].w;
      if (BN_IN) {
        const float4 s0 = *(const float4*)&s_sc[kc * 32 + q * 8];
        const float4 s1 = *(const float4*)&s_sc[kc * 32 + q * 8 + 4];
        const float4 h0 = *(const float4*)&s_sh[kc * 32 + q * 8];
        const float4 h1 = *(const float4*)&s_sh[kc * 32 + q * 8 + 4];
        a[0] = fmaxf(fmaf(a[0], s0.x, h0.x), 0.f);
        a[1] = fmaxf(fmaf(a[1], s0.y, h0.y), 0.f);
        a[2] = fmaxf(fmaf(a[2], s0.z, h0.z), 0.f);
        a[3] = fmaxf(fmaf(a[3], s0.w, h0.w), 0.f);
        a[4] = fmaxf(fmaf(a[4], s1.x, h1.x), 0.f);
        a[5] = fmaxf(fmaf(a[5], s1.y, h1.y), 0.f);
        a[6] = fmaxf(fmaf(a[6], s1.z, h1.z), 0.f);
        a[7] = fmaxf(fmaf(a[7], s1.w, h1.w), 0.f);
      }
      sv8 ahi, alo;
#pragma unroll
      for (int j = 0; j < 8; ++j) {
        unsigned short h = f2bf(a[j]);
        ahi[j] = (short)h;
        alo[j] = (short)f2bf(a[j] - bf2f(h));
      }
#pragma unroll
      for (int nt = 0; nt < 8; ++nt) {
        sv8 bh = bsh[kc * 512 + nt * 64 + lane];
        sv8 bl = bsl[kc * 512 + nt * 64 + lane];
        acc[nt] = __builtin_amdgcn_mfma_f32_16x16x32_bf16(ahi, bh, acc[nt], 0, 0, 0);
        acc[nt] = __builtin_amdgcn_mfma_f32_16x16x32_bf16(alo, bh, acc[nt], 0, 0, 0);
        acc[nt] = __builtin_amdgcn_mfma_f32_16x16x32_bf16(ahi, bl, acc[nt], 0, 0, 0);
      }
    }
    // ---- epilogue: C/D layout col=nt*16+c, row=wave*16+q*4+reg ----
#pragma unroll
    for (int nt = 0; nt < 8; ++nt) {
      int colg = nt * 16 + c;
#pragma unroll
      for (int reg = 0; reg < 4; ++reg) {
        int g = tbase + wave * 16 + q * 4 + reg;
        if (g < n) {
          float v = acc[nt][reg] + bv[nt];
          if (OUT_BF16)
            outb[(size_t)g * 128 + colg] = f2bf(v);
          else
            outf[(size_t)g * 128 + colg] = v;
        }
      }
    }
  };
  tile(va0, base);
  if (base + 64 < n) tile(va1, base + 64);
}

// ---------------- launch ----------------
extern "C" void kernel_launch(void* const* d_in, const int* in_sizes, int n_in,
                              void* d_out, int out_size, void* d_ws, size_t ws_size,
                              hipStream_t stream) {
  const float* x   = (const float*)d_in[0];
  const int*   ei  = (const int*)d_in[1];
  const float* eps = (const float*)d_in[2];
  const float* W1  = (const float*)d_in[3];
  const float* b1  = (const float*)d_in[4];
  const float* g1  = (const float*)d_in[5];
  const float* be1 = (const float*)d_in[6];
  const float* W2  = (const float*)d_in[7];
  const float* b2  = (const float*)d_in[8];
  const float* bng = (const float*)d_in[9];
  const float* bnb = (const float*)d_in[10];
  int n = in_sizes[0] / 128;
  int E = in_sizes[1] / 2;

  char* ws = (char*)d_ws;
  size_t off = 0;
  auto alloc = [&](size_t bytes) -> void* {
    void* p = ws + off;
    off += (bytes + 255) & ~(size_t)255;
    return p;
  };
  // cnt and ST first + adjacent -> single zeroing range covers both
  int*   cnt  = (int*)alloc((size_t)(n + 1) * 4);   // cnt[n] + ocnt
  int*   ocnt = cnt + n;
  float* ST   = (float*)alloc((size_t)5 * REP * 256 * 4);  // 5 pairs x REP x (sum|sq)
  int zwords = (int)(((char*)(ST + (size_t)5 * REP * 256) - (char*)cnt) / 4);
  int*   ovf  = (int*)alloc((size_t)MAXOVF * 2 * 4);
  unsigned short* ell = (unsigned short*)alloc((size_t)n * ELLK * 2);
  float* agg  = (float*)alloc((size_t)n * 128 * 4);
  float* y1   = (float*)alloc((size_t)n * 128 * 4);
  unsigned short* y2b = (unsigned short*)alloc((size_t)n * 128 * 2);
  unsigned short* xbf = (unsigned short*)alloc((size_t)n * 128 * 2);
  unsigned short* wbh = (unsigned short*)alloc(6 * 16384 * 2);
  unsigned short* wbl = (unsigned short*)alloc(6 * 16384 * 2);
  int nb = (E + 1023) / 1024;
  int chunk = (E + nb - 1) / nb;           // <= 1024 by construction
  int np = (n + P2N - 1) >> PSH;           // <= 256 (n fits u16)
  unsigned* seg = (unsigned*)alloc((size_t)nb * chunk * 4);
  int* lens = (int*)alloc((size_t)nb * np * 4);
  int* offs = (int*)alloc((size_t)nb * np * 4);

  // prep first: zeroes cnt+ocnt+ST (blocks 48..111), W fragments, x bf16 cast
  int total4 = n * 32;
  k_prep<<<48 + ZBLK + (total4 + 255) / 256, 256, 0, stream>>>(
      x, xbf, total4, W1, W2, wbh, wbl, cnt, zwords);
  // two-phase ELL build: partition-sorted private segments -> per-partition LDS assembly
  k_bucket<<<nb, 256, 0, stream>>>(ei, seg, lens, offs, E, chunk, np);
  k_build<<<np, 256, 0, stream>>>(seg, lens, offs, cnt, ell, ovf, ocnt, nb, chunk, n, np);

  int ntiles2 = (n + 127) / 128;
  int gatherb = 2048;
  int statb = 512;
  float inv_n = 1.0f / (float)n;
  for (int l = 0; l < 3; ++l) {
    float* stA = ST + (size_t)(l * 2) * REP * 256;
    float* stB = ST + (size_t)(l * 2 + 1) * REP * 256;
    const unsigned short* w1h = wbh + (size_t)l * 16384;
    const unsigned short* w1l = wbl + (size_t)l * 16384;
    const unsigned short* w2h = wbh + (size_t)(3 + l) * 16384;
    const unsigned short* w2l = wbl + (size_t)(3 + l) * 16384;
    // 1) aggregation (folds previous inter-layer BN+ReLU for l>0), bf16 + ELL
    if (l == 0) {
      k_gather<false><<<gatherb, 256, 0, stream>>>(
          xbf, nullptr, nullptr, nullptr, inv_n, cnt, ell, ovf, ocnt, eps, l, agg, n);
    } else {
      float* stPrev = ST + (size_t)((l - 1) * 2 + 1) * REP * 256;
      k_gather<true><<<gatherb, 256, 0, stream>>>(
          y2b, stPrev, bng + (size_t)(l - 1) * 128, bnb + (size_t)(l - 1) * 128, inv_n,
          cnt, ell, ovf, ocnt, eps, l, agg, n);
    }
    // 2) GEMM1 + bias (pure) -> y1 fp32
    k_gemm_mfma<false, false><<<ntiles2, 256, 0, stream>>>(
        agg, nullptr, nullptr, nullptr, inv_n, w1h, w1l, b1 + (size_t)l * 128,
        y1, nullptr, n);
    // 3) column stats of y1 -> stA
    k_stats<false><<<statb, 256, 0, stream>>>(y1, stA, n);
    // 4) GEMM2 with in-prologue BN finalize + BN+ReLU on load
    if (l < 2) {
      k_gemm_mfma<true, true><<<ntiles2, 256, 0, stream>>>(
          y1, stA, g1 + (size_t)l * 128, be1 + (size_t)l * 128, inv_n,
          w2h, w2l, b2 + (size_t)l * 128, nullptr, y2b, n);
      // 5) column stats of y2 (bf16) -> stB
      k_stats<true><<<statb, 256, 0, stream>>>(y2b, stB, n);
    } else {
      k_gemm_mfma<true, false><<<ntiles2, 256, 0, stream>>>(
          y1, stA, g1 + (size_t)l * 128, be1 + (size_t)l * 128, inv_n,
          w2h, w2l, b2 + (size_t)l * 128, (float*)d_out, nullptr, n);
    }
  }
}

// Round 14
// 356.404 us; speedup vs baseline: 1.4816x; 1.0036x over previous
//
#include <hip/hip_runtime.h>
#include <stddef.h>

#define TBN_EPS 1e-5f
#define ELLK 32          // Poisson(16): P(deg>32)~1.4e-4 -> ~7 nodes overflow
#define MAXOVF 4096
#define PSH 8            // 256-node partitions (np = ceil(n/256) <= 256)
#define P2N 256
#define REP 16           // stat replica slots
#define ZBLK 64

typedef short sv8 __attribute__((ext_vector_type(8)));     // 8 bf16 (4 VGPRs)
typedef float fv4 __attribute__((ext_vector_type(4)));     // MFMA C/D

__device__ inline unsigned short f2bf(float f) {  // RNE float -> bf16 bits
  unsigned u = __float_as_uint(f);
  u += 0x7FFF + ((u >> 16) & 1);
  return (unsigned short)(u >> 16);
}
__device__ inline float bf2f(unsigned short h) {
  return __uint_as_float(((unsigned)h) << 16);
}

// ------- merged: zeroing + W-frag prep + x cast + phase-1 partition bucket -------
// Roles by blockIdx: [0,48) W prep | [48,48+ZBLK) zero ocnt+ST | [.., +xb) x cast |
// rest: bucket — each block partition-sorts a private <=1024-edge chunk in LDS and
// writes one coalesced packed segment + {len,off} tables. All roles independent.
__global__ __launch_bounds__(256) void k_prep(
    const float* __restrict__ x, unsigned short* __restrict__ xb, int total4,
    const float* __restrict__ W1, const float* __restrict__ W2,
    unsigned short* __restrict__ wbh, unsigned short* __restrict__ wbl,
    int* __restrict__ zbase, int zwords, int xblocks,
    const int* __restrict__ ei, unsigned* __restrict__ seg,
    int* __restrict__ lens, int* __restrict__ offs, int E, int chunk, int np) {
  int b = blockIdx.x, tid = threadIdx.x;
  if (b < 48) {  // W prep: 48 blocks = 8 x 3 layers x 2 matrices
    int bz = b / 24, by = (b % 24) / 8, bx = b % 8;
    int ent = bx * 256 + tid;   // (kc*8+nt)*64+lane
    int lane = ent & 63;
    int t = ent >> 6;
    int nt = t & 7;
    int kc = t >> 3;
    const float* W = (bz ? W2 : W1) + (size_t)by * 16384;
    size_t mbase = (size_t)(bz * 3 + by) * 16384;
    int q = lane >> 4, cc = lane & 15;
    int col = nt * 16 + cc;
    size_t obase = mbase + (size_t)ent * 8;
#pragma unroll
    for (int j = 0; j < 8; ++j) {
      float w = W[(size_t)(kc * 32 + q * 8 + j) * 128 + col];
      unsigned short h = f2bf(w);
      unsigned short l = f2bf(w - bf2f(h));
      wbh[obase + j] = h;
      wbl[obase + j] = l;
    }
  } else if (b < 48 + ZBLK) {  // zero ocnt + ST (cnt NOT zeroed: k_build writes all)
    int i = (b - 48) * 256 + tid;
    int stride = ZBLK * 256;
    for (; i < zwords; i += stride) zbase[i] = 0;
  } else if (b < 48 + ZBLK + xblocks) {
    int i = (b - 48 - ZBLK) * 256 + tid;
    if (i < total4) {
      float4 v = ((const float4*)x)[i];
      ushort4 o;
      o.x = f2bf(v.x); o.y = f2bf(v.y); o.z = f2bf(v.z); o.w = f2bf(v.w);
      ((ushort4*)xb)[i] = o;
    }
  } else {  // phase-1 bucket
    __shared__ int s_nz;
    __shared__ int s_cnt[256], s_pos[256];
    __shared__ unsigned s_buf[1024];
    int bb = b - 48 - ZBLK - xblocks;
    if (tid == 0) s_nz = 0;
    for (int i = tid; i < np; i += 256) s_cnt[i] = 0;
    __syncthreads();
    {
      int idx = 2 * tid + 1;
      int v = (idx < E) ? ei[idx] : 0;   // odd dwords: i64 high-halves vs i32 payload
      if (v != 0) atomicOr(&s_nz, 1);
    }
    __syncthreads();
    bool i64 = (s_nz == 0);
    const int2* ei64s = (const int2*)ei;
    const int2* ei64d = (const int2*)(ei + 2 * (size_t)E);
    int e0 = bb * chunk;
    int ecnt = E - e0;
    ecnt = (ecnt < chunk) ? ecnt : chunk;
    if (ecnt < 0) ecnt = 0;
    unsigned pk[4];
    int part[4];
    int nk = 0;
    for (int i = tid; i < ecnt; i += 256, ++nk) {
      int e = e0 + i;
      int d = i64 ? ei64d[e].x : ei[(size_t)E + e];
      int s = i64 ? ei64s[e].x : ei[e];
      pk[nk] = (unsigned)(s & 0xFFFF) | ((unsigned)(d & (P2N - 1)) << 16);
      part[nk] = d >> PSH;
      atomicAdd(&s_cnt[part[nk]], 1);
    }
    __syncthreads();
    if (tid == 0) {
      int acc = 0;
      for (int c = 0; c < np; ++c) { s_pos[c] = acc; acc += s_cnt[c]; }
    }
    __syncthreads();
    for (int i = tid; i < np; i += 256) {  // emit tables BEFORE scatter mutates s_pos
      lens[(size_t)bb * np + i] = s_cnt[i];
      offs[(size_t)bb * np + i] = s_pos[i];
    }
    __syncthreads();
    for (int k = 0; k < nk; ++k) {
      int p = atomicAdd(&s_pos[part[k]], 1);
      s_buf[p] = pk[k];
    }
    __syncthreads();
    unsigned* out = seg + (size_t)bb * chunk;
    for (int i = tid; i < ecnt; i += 256) out[i] = s_buf[i];
  }
}

// ---------------- phase 2: per-partition LDS ELL assembly ----------------
__global__ __launch_bounds__(256) void k_build(
    const unsigned* __restrict__ seg, const int* __restrict__ lens,
    const int* __restrict__ offs, int* __restrict__ cnt,
    unsigned short* __restrict__ ell, int* __restrict__ ovf, int* __restrict__ ocnt,
    int nb, int chunk, int n, int np) {
  __shared__ unsigned short s_ell[P2N * ELLK];   // 16 KB
  __shared__ int s_cnt[P2N];                     // 1 KB
  int p = blockIdx.x, tid = threadIdx.x;
  int node0 = p << PSH;
  for (int i = tid; i < P2N; i += 256) s_cnt[i] = 0;
  __syncthreads();
  for (int b = tid; b < nb; b += 256) {
    int len = lens[(size_t)b * np + p];
    int off = offs[(size_t)b * np + p];
    const unsigned* sp = seg + (size_t)b * chunk + off;
    for (int i = 0; i < len; ++i) {
      unsigned pkv = sp[i];
      int dl = (int)(pkv >> 16);
      int pos = atomicAdd(&s_cnt[dl], 1);
      if (pos < ELLK) {
        s_ell[dl * ELLK + pos] = (unsigned short)(pkv & 0xFFFF);
      } else {
        int o = atomicAdd(ocnt, 1);
        if (o < MAXOVF) { ovf[2 * o] = (int)(pkv & 0xFFFF); ovf[2 * o + 1] = node0 + dl; }
      }
    }
  }
  __syncthreads();
  int rows = n - node0;
  rows = (rows < P2N) ? rows : P2N;
  if (rows <= 0) return;
  for (int i = tid; i < rows; i += 256) cnt[node0 + i] = s_cnt[i];
  int tot16 = rows * 4;   // rows * 64B as uint4
  const uint4* src4 = (const uint4*)s_ell;
  uint4* dst4 = (uint4*)(ell + (size_t)node0 * ELLK);
  for (int i = tid; i < tot16; i += 256) dst4[i] = src4[i];
}

// ---------------- gather: agg = (1+eps)*f(x[g]) + sum f(x[src]), bf16 + ELL -------
// 16-wide load batches double outstanding VMEM per wave (vs 8) for L3 latency hiding.
template <bool BN>
__global__ __launch_bounds__(256, 8) void k_gather(
    const unsigned short* __restrict__ xin, const float* __restrict__ stats,
    const float* __restrict__ gamma, const float* __restrict__ beta, float inv_n,
    const int* __restrict__ cnt, const unsigned short* __restrict__ ell,
    const int* __restrict__ ovf, const int* __restrict__ ocnt,
    const float* __restrict__ eps_arr, int layer, float* __restrict__ agg, int n) {
  __shared__ float s_sc[128], s_sh[128];
  if (BN) {
    int i = threadIdx.x;
    if (i < 128) {
      float s = 0.f, q = 0.f;
#pragma unroll
      for (int r = 0; r < REP; ++r) { s += stats[r * 256 + i]; q += stats[r * 256 + 128 + i]; }
      float m = s * inv_n;
      float var = q * inv_n - m * m;
      float scale = rsqrtf(var + TBN_EPS) * gamma[i];
      s_sc[i] = scale;
      s_sh[i] = beta[i] - m * scale;
    }
    __syncthreads();
  }
  int lane = threadIdx.x & 63;
  int wid = blockIdx.x * (blockDim.x >> 6) + (threadIdx.x >> 6);
  int nw = gridDim.x * (blockDim.x >> 6);
  float ep = 1.0f + eps_arr[layer];
  float sc0 = 1.f, sh0 = 0.f, sc1 = 1.f, sh1 = 0.f;
  if (BN) {
    float2 s2 = ((const float2*)s_sc)[lane];
    float2 h2 = ((const float2*)s_sh)[lane];
    sc0 = s2.x; sc1 = s2.y; sh0 = h2.x; sh1 = h2.y;
  }
  const unsigned* xb = (const unsigned*)xin;  // one dword = 2 bf16 cols
  for (int g = wid; g < n; g += nw) {
    int deg0 = cnt[g];
    int deg = (deg0 < ELLK) ? deg0 : ELLK;
    const unsigned short* row = ell + (size_t)g * ELLK;
    unsigned r = xb[(size_t)g * 64 + lane];
    float vx = __uint_as_float(r << 16);
    float vy = __uint_as_float(r & 0xFFFF0000u);
    if (BN) {
      vx = fmaxf(fmaf(vx, sc0, sh0), 0.f);
      vy = fmaxf(fmaf(vy, sc1, sh1), 0.f);
    }
    float ax = ep * vx, ay = ep * vy;
    int j = 0;
    for (; j + 15 < deg; j += 16) {
      unsigned rr[16];
#pragma unroll
      for (int jj = 0; jj < 16; ++jj) rr[jj] = xb[(size_t)row[j + jj] * 64 + lane];
#pragma unroll
      for (int jj = 0; jj < 16; ++jj) {
        float xv = __uint_as_float(rr[jj] << 16);
        float yv = __uint_as_float(rr[jj] & 0xFFFF0000u);
        if (BN) {
          xv = fmaxf(fmaf(xv, sc0, sh0), 0.f);
          yv = fmaxf(fmaf(yv, sc1, sh1), 0.f);
        }
        ax += xv; ay += yv;
      }
    }
    for (; j + 7 < deg; j += 8) {
      unsigned rr[8];
#pragma unroll
      for (int jj = 0; jj < 8; ++jj) rr[jj] = xb[(size_t)row[j + jj] * 64 + lane];
#pragma unroll
      for (int jj = 0; jj < 8; ++jj) {
        float xv = __uint_as_float(rr[jj] << 16);
        float yv = __uint_as_float(rr[jj] & 0xFFFF0000u);
        if (BN) {
          xv = fmaxf(fmaf(xv, sc0, sh0), 0.f);
          yv = fmaxf(fmaf(yv, sc1, sh1), 0.f);
        }
        ax += xv; ay += yv;
      }
    }
    for (; j + 3 < deg; j += 4) {
      unsigned rr[4];
#pragma unroll
      for (int jj = 0; jj < 4; ++jj) rr[jj] = xb[(size_t)row[j + jj] * 64 + lane];
#pragma unroll
      for (int jj = 0; jj < 4; ++jj) {
        float xv = __uint_as_float(rr[jj] << 16);
        float yv = __uint_as_float(rr[jj] & 0xFFFF0000u);
        if (BN) {
          xv = fmaxf(fmaf(xv, sc0, sh0), 0.f);
          yv = fmaxf(fmaf(yv, sc1, sh1), 0.f);
        }
        ax += xv; ay += yv;
      }
    }
    for (; j < deg; ++j) {
      unsigned r0 = xb[(size_t)row[j] * 64 + lane];
      float x0 = __uint_as_float(r0 << 16), y0 = __uint_as_float(r0 & 0xFFFF0000u);
      if (BN) {
        x0 = fmaxf(fmaf(x0, sc0, sh0), 0.f);
        y0 = fmaxf(fmaf(y0, sc1, sh1), 0.f);
      }
      ax += x0; ay += y0;
    }
    if (deg0 > ELLK) {  // rare: scan tiny overflow list for this dst
      int oc = *ocnt;
      oc = (oc < MAXOVF) ? oc : MAXOVF;
      for (int i = 0; i < oc; ++i) {
        if (ovf[2 * i + 1] == g) {
          unsigned r0 = xb[(size_t)ovf[2 * i] * 64 + lane];
          float x0 = __uint_as_float(r0 << 16), y0 = __uint_as_float(r0 & 0xFFFF0000u);
          if (BN) {
            x0 = fmaxf(fmaf(x0, sc0, sh0), 0.f);
            y0 = fmaxf(fmaf(y0, sc1, sh1), 0.f);
          }
          ax += x0; ay += y0;
        }
      }
    }
    ((float2*)agg)[(size_t)g * 64 + lane] = make_float2(ax, ay);
  }
}

// ---------------- column stats: sum / sumsq per column -> REP-replicated table ----
template <bool BF16IN>
__global__ __launch_bounds__(256) void k_stats(
    const void* __restrict__ in, float* __restrict__ st, int n) {
  __shared__ float sm_sum[4][128], sm_sq[4][128];
  int tid = threadIdx.x;
  int c = tid & 63;       // handles cols 2c, 2c+1
  int rg = tid >> 6;      // 4 row-groups
  float s0 = 0.f, s1 = 0.f, q0 = 0.f, q1 = 0.f;
  for (int r = blockIdx.x * 4 + rg; r < n; r += gridDim.x * 4) {
    float a, b;
    if (BF16IN) {
      unsigned v = ((const unsigned*)in)[(size_t)r * 64 + c];
      a = __uint_as_float(v << 16);
      b = __uint_as_float(v & 0xFFFF0000u);
    } else {
      float2 v = ((const float2*)in)[(size_t)r * 64 + c];
      a = v.x; b = v.y;
    }
    s0 += a; s1 += b; q0 += a * a; q1 += b * b;
  }
  sm_sum[rg][2 * c] = s0; sm_sum[rg][2 * c + 1] = s1;
  sm_sq[rg][2 * c] = q0;  sm_sq[rg][2 * c + 1] = q1;
  __syncthreads();
  if (tid < 128) {
    float s = 0.f, q = 0.f;
#pragma unroll
    for (int g = 0; g < 4; ++g) { s += sm_sum[g][tid]; q += sm_sq[g][tid]; }
    float* base = st + (size_t)(blockIdx.x & (REP - 1)) * 256;
    atomicAdd(&base[tid], s);
    atomicAdd(&base[128 + tid], q);
  }
}

// ---------------- MFMA GEMM: 128 rows (2 sub-tiles) per block, B in LDS ----------
template <bool BN_IN, bool OUT_BF16>
__global__ __launch_bounds__(256) void k_gemm_mfma(
    const float* __restrict__ in, const float* __restrict__ bn_stats,
    const float* __restrict__ bn_gamma, const float* __restrict__ bn_beta, float inv_n,
    const unsigned short* __restrict__ wh, const unsigned short* __restrict__ wl,
    const float* __restrict__ bias, float* __restrict__ outf,
    unsigned short* __restrict__ outb, int n) {
  __shared__ unsigned short Bs[32768];   // 64 KB: [0..2047]=hi sv8, [2048..4095]=lo
  __shared__ float s_sc[128], s_sh[128];
  int tid = threadIdx.x;
  int wave = tid >> 6, lane = tid & 63;
  int q = lane >> 4, c = lane & 15;
  int base = blockIdx.x * 128;
  auto loadA = [&](int row, float4* v) {
    bool valid = row < n;
#pragma unroll
    for (int kc = 0; kc < 4; ++kc) {
      v[kc * 2] = make_float4(0.f, 0.f, 0.f, 0.f);
      v[kc * 2 + 1] = make_float4(0.f, 0.f, 0.f, 0.f);
      if (valid) {
        const float* p = &in[(size_t)row * 128 + kc * 32 + q * 8];
        v[kc * 2] = *(const float4*)p;
        v[kc * 2 + 1] = *(const float4*)(p + 4);
      }
    }
  };
  float4 va0[8], va1[8];
  loadA(base + wave * 16 + c, va0);   // sub-tile 0 A in flight during B stage
  // bulk cooperative B stage (pipelined 16B loads)
  {
    const sv8* whv = (const sv8*)wh;
    const sv8* wlv = (const sv8*)wl;
    sv8* bs = (sv8*)Bs;
#pragma unroll
    for (int r = 0; r < 8; ++r) {
      bs[tid + 256 * r] = whv[tid + 256 * r];
      bs[2048 + tid + 256 * r] = wlv[tid + 256 * r];
    }
  }
  if (BN_IN && tid < 128) {
    float s = 0.f, qq = 0.f;
#pragma unroll
    for (int r = 0; r < REP; ++r) { s += bn_stats[r * 256 + tid]; qq += bn_stats[r * 256 + 128 + tid]; }
    float m = s * inv_n;
    float var = qq * inv_n - m * m;
    float scale = rsqrtf(var + TBN_EPS) * bn_gamma[tid];
    s_sc[tid] = scale;
    s_sh[tid] = bn_beta[tid] - m * scale;
  }
  float bv[8];
#pragma unroll
  for (int nt = 0; nt < 8; ++nt) bv[nt] = bias[nt * 16 + c];
  const sv8* bsh = (const sv8*)Bs;
  const sv8* bsl = ((const sv8*)Bs) + 2048;
  __syncthreads();
  loadA(base + 64 + wave * 16 + c, va1);  // sub-tile 1 A flies under tile-0 MFMA
  auto tile = [&](const float4* va, int tbase) {
    fv4 acc[8];
#pragma unroll
    for (int nt = 0; nt < 8; ++nt) acc[nt] = (fv4){0.f, 0.f, 0.f, 0.f};
#pragma unroll
    for (int kc = 0; kc < 4; ++kc) {
      float a[8];
      a[0] = va[kc * 2].x; a[1] = va[kc * 2].y; a[2] = va[kc * 2].z; a[3] = va[kc * 2].w;
      a[4] = va[kc * 2 + 1].x; a[5] = va[kc * 2 + 1].y;
      a[6] = va[kc * 2 + 1].z; a[7] = va[kc * 2 + 1].w;
      if (BN_IN) {
        const float4 s0 = *(const float4*)&s_sc[kc * 32 + q * 8];
        const float4 s1 = *(const float4*)&s_sc[kc * 32 + q * 8 + 4];
        const float4 h0 = *(const float4*)&s_sh[kc * 32 + q * 8];
        const float4 h1 = *(const float4*)&s_sh[kc * 32 + q * 8 + 4];
        a[0] = fmaxf(fmaf(a[0], s0.x, h0.x), 0.f);
        a[1] = fmaxf(fmaf(a[1], s0.y, h0.y), 0.f);
        a[2] = fmaxf(fmaf(a[2], s0.z, h0.z), 0.f);
        a[3] = fmaxf(fmaf(a[3], s0.w, h0.w), 0.f);
        a[4] = fmaxf(fmaf(a[4], s1.x, h1.x), 0.f);
        a[5] = fmaxf(fmaf(a[5], s1.y, h1.y), 0.f);
        a[6] = fmaxf(fmaf(a[6], s1.z, h1.z), 0.f);
        a[7] = fmaxf(fmaf(a[7], s1.w, h1.w), 0.f);
      }
      sv8 ahi, alo;
#pragma unroll
      for (int j = 0; j < 8; ++j) {
        unsigned short h = f2bf(a[j]);
        ahi[j] = (short)h;
        alo[j] = (short)f2bf(a[j] - bf2f(h));
      }
#pragma unroll
      for (int nt = 0; nt < 8; ++nt) {
        sv8 bh = bsh[kc * 512 + nt * 64 + lane];
        sv8 bl = bsl[kc * 512 + nt * 64 + lane];
        acc[nt] = __builtin_amdgcn_mfma_f32_16x16x32_bf16(ahi, bh, acc[nt], 0, 0, 0);
        acc[nt] = __builtin_amdgcn_mfma_f32_16x16x32_bf16(alo, bh, acc[nt], 0, 0, 0);
        acc[nt] = __builtin_amdgcn_mfma_f32_16x16x32_bf16(ahi, bl, acc[nt], 0, 0, 0);
      }
    }
    // ---- epilogue: C/D layout col=nt*16+c, row=wave*16+q*4+reg ----
#pragma unroll
    for (int nt = 0; nt < 8; ++nt) {
      int colg = nt * 16 + c;
#pragma unroll
      for (int reg = 0; reg < 4; ++reg) {
        int g = tbase + wave * 16 + q * 4 + reg;
        if (g < n) {
          float v = acc[nt][reg] + bv[nt];
          if (OUT_BF16)
            outb[(size_t)g * 128 + colg] = f2bf(v);
          else
            outf[(size_t)g * 128 + colg] = v;
        }
      }
    }
  };
  tile(va0, base);
  if (base + 64 < n) tile(va1, base + 64);
}

// ---------------- launch ----------------
extern "C" void kernel_launch(void* const* d_in, const int* in_sizes, int n_in,
                              void* d_out, int out_size, void* d_ws, size_t ws_size,
                              hipStream_t stream) {
  const float* x   = (const float*)d_in[0];
  const int*   ei  = (const int*)d_in[1];
  const float* eps = (const float*)d_in[2];
  const float* W1  = (const float*)d_in[3];
  const float* b1  = (const float*)d_in[4];
  const float* g1  = (const float*)d_in[5];
  const float* be1 = (const float*)d_in[6];
  const float* W2  = (const float*)d_in[7];
  const float* b2  = (const float*)d_in[8];
  const float* bng = (const float*)d_in[9];
  const float* bnb = (const float*)d_in[10];
  int n = in_sizes[0] / 128;
  int E = in_sizes[1] / 2;

  char* ws = (char*)d_ws;
  size_t off = 0;
  auto alloc = [&](size_t bytes) -> void* {
    void* p = ws + off;
    off += (bytes + 255) & ~(size_t)255;
    return p;
  };
  // zero zone first: ocnt (padded to 256B) + ST, contiguous
  int*   ocnt = (int*)alloc(4);
  float* ST   = (float*)alloc((size_t)5 * REP * 256 * 4);  // 5 pairs x REP x (sum|sq)
  int zwords = (int)(((char*)(ST + (size_t)5 * REP * 256) - (char*)ocnt) / 4);
  int*   cnt  = (int*)alloc((size_t)n * 4);   // fully written by k_build each run
  int*   ovf  = (int*)alloc((size_t)MAXOVF * 2 * 4);
  unsigned short* ell = (unsigned short*)alloc((size_t)n * ELLK * 2);
  float* agg  = (float*)alloc((size_t)n * 128 * 4);
  float* y1   = (float*)alloc((size_t)n * 128 * 4);
  unsigned short* y2b = (unsigned short*)alloc((size_t)n * 128 * 2);
  unsigned short* xbf = (unsigned short*)alloc((size_t)n * 128 * 2);
  unsigned short* wbh = (unsigned short*)alloc(6 * 16384 * 2);
  unsigned short* wbl = (unsigned short*)alloc(6 * 16384 * 2);
  int nb = (E + 1023) / 1024;
  int chunk = (E + nb - 1) / nb;           // <= 1024 by construction
  int np = (n + P2N - 1) >> PSH;           // <= 256 (n fits u16)
  unsigned* seg = (unsigned*)alloc((size_t)nb * chunk * 4);
  int* lens = (int*)alloc((size_t)nb * np * 4);
  int* offs = (int*)alloc((size_t)nb * np * 4);

  // merged prep: W frags + zero + x cast + phase-1 bucket (independent roles)
  int total4 = n * 32;
  int xblocks = (total4 + 255) / 256;
  k_prep<<<48 + ZBLK + xblocks + nb, 256, 0, stream>>>(
      x, xbf, total4, W1, W2, wbh, wbl, ocnt, zwords, xblocks,
      ei, seg, lens, offs, E, chunk, np);
  // phase-2 ELL assembly
  k_build<<<np, 256, 0, stream>>>(seg, lens, offs, cnt, ell, ovf, ocnt, nb, chunk, n, np);

  int ntiles2 = (n + 127) / 128;
  int gatherb = 2048;
  int statb = 512;
  float inv_n = 1.0f / (float)n;
  for (int l = 0; l < 3; ++l) {
    float* stA = ST + (size_t)(l * 2) * REP * 256;
    float* stB = ST + (size_t)(l * 2 + 1) * REP * 256;
    const unsigned short* w1h = wbh + (size_t)l * 16384;
    const unsigned short* w1l = wbl + (size_t)l * 16384;
    const unsigned short* w2h = wbh + (size_t)(3 + l) * 16384;
    const unsigned short* w2l = wbl + (size_t)(3 + l) * 16384;
    // 1) aggregation (folds previous inter-layer BN+ReLU for l>0), bf16 + ELL
    if (l == 0) {
      k_gather<false><<<gatherb, 256, 0, stream>>>(
          xbf, nullptr, nullptr, nullptr, inv_n, cnt, ell, ovf, ocnt, eps, l, agg, n);
    } else {
      float* stPrev = ST + (size_t)((l - 1) * 2 + 1) * REP * 256;
      k_gather<true><<<gatherb, 256, 0, stream>>>(
          y2b, stPrev, bng + (size_t)(l - 1) * 128, bnb + (size_t)(l - 1) * 128, inv_n,
          cnt, ell, ovf, ocnt, eps, l, agg, n);
    }
    // 2) GEMM1 + bias (pure) -> y1 fp32
    k_gemm_mfma<false, false><<<ntiles2, 256, 0, stream>>>(
        agg, nullptr, nullptr, nullptr, inv_n, w1h, w1l, b1 + (size_t)l * 128,
        y1, nullptr, n);
    // 3) column stats of y1 -> stA
    k_stats<false><<<statb, 256, 0, stream>>>(y1, stA, n);
    // 4) GEMM2 with in-prologue BN finalize + BN+ReLU on load
    if (l < 2) {
      k_gemm_mfma<true, true><<<ntiles2, 256, 0, stream>>>(
          y1, stA, g1 + (size_t)l * 128, be1 + (size_t)l * 128, inv_n,
          w2h, w2l, b2 + (size_t)l * 128, nullptr, y2b, n);
      // 5) column stats of y2 (bf16) -> stB
      k_stats<true><<<statb, 256, 0, stream>>>(y2b, stB, n);
    } else {
      k_gemm_mfma<true, false><<<ntiles2, 256, 0, stream>>>(
          y1, stA, g1 + (size_t)l * 128, be1 + (size_t)l * 128, inv_n,
          w2h, w2l, b2 + (size_t)l * 128, (float*)d_out, nullptr, n);
    }
  }
}